// Round 2
// baseline (5361.236 us; speedup 1.0000x reference)
//
#include <hip/hip_runtime.h>
#include <hip/hip_bf16.h>

#define D_EMBED 1024
#define N_HEADS 16
#define HEAD_DIM 64
#define BATCH 2
#define SEQ 2048
#define ROWS (BATCH * SEQ)          // 4096
#define QKV_COLS (3 * D_EMBED)      // 3072

// ---------------------------------------------------------------------------
// Generic GEMM: C[M,N] = A[M,K] @ B[K,N] + bias[N]; fp32 in/out/accum.
// 64x64 tile, BK=16, 256 threads, 4x4 micro-tile per thread.
// Requires M%64==0, N%64==0, K%16==0 (true for all our shapes).
// ---------------------------------------------------------------------------
__global__ __launch_bounds__(256)
void gemm_bias_f32(const float* __restrict__ A, const float* __restrict__ B,
                   const float* __restrict__ bias, float* __restrict__ C,
                   int M, int N, int K)
{
    __shared__ float As[64][17];   // [m][k], +1 pad
    __shared__ float Bs[16][68];   // [k][n], +4 pad

    const int tid = threadIdx.x;
    const int tx = tid & 15;       // n-group
    const int ty = tid >> 4;       // m-group
    const int blockM = blockIdx.y * 64;
    const int blockN = blockIdx.x * 64;

    // A-load mapping: row = tid>>2 (64 rows), 4 consecutive k per thread
    const int a_row = tid >> 2;
    const int a_kcol = (tid & 3) * 4;
    // B-load mapping: row = tid>>4 (16 rows), 4 consecutive n per thread
    const int b_row = tid >> 4;
    const int b_ncol = (tid & 15) * 4;

    float acc[4][4];
#pragma unroll
    for (int i = 0; i < 4; ++i)
#pragma unroll
        for (int j = 0; j < 4; ++j) acc[i][j] = 0.f;

    for (int k0 = 0; k0 < K; k0 += 16) {
        // stage A tile (float4 global load, scalar LDS stores into padded tile)
        {
            const float4 av = *reinterpret_cast<const float4*>(
                A + (size_t)(blockM + a_row) * K + (k0 + a_kcol));
            As[a_row][a_kcol + 0] = av.x;
            As[a_row][a_kcol + 1] = av.y;
            As[a_row][a_kcol + 2] = av.z;
            As[a_row][a_kcol + 3] = av.w;
        }
        // stage B tile
        {
            const float4 bv = *reinterpret_cast<const float4*>(
                B + (size_t)(k0 + b_row) * N + (blockN + b_ncol));
            Bs[b_row][b_ncol + 0] = bv.x;
            Bs[b_row][b_ncol + 1] = bv.y;
            Bs[b_row][b_ncol + 2] = bv.z;
            Bs[b_row][b_ncol + 3] = bv.w;
        }
        __syncthreads();

#pragma unroll
        for (int kk = 0; kk < 16; ++kk) {
            float a[4], b[4];
#pragma unroll
            for (int i = 0; i < 4; ++i) a[i] = As[ty * 4 + i][kk];
#pragma unroll
            for (int j = 0; j < 4; ++j) b[j] = Bs[kk][tx * 4 + j];
#pragma unroll
            for (int i = 0; i < 4; ++i)
#pragma unroll
                for (int j = 0; j < 4; ++j) acc[i][j] += a[i] * b[j];
        }
        __syncthreads();
    }

#pragma unroll
    for (int i = 0; i < 4; ++i) {
        const int row = blockM + ty * 4 + i;
#pragma unroll
        for (int j = 0; j < 4; ++j) {
            const int col = blockN + tx * 4 + j;
            C[(size_t)row * N + col] = acc[i][j] + bias[col];
        }
    }
}

// ---------------------------------------------------------------------------
// Causal attention, online softmax. One wave (64 lanes) per (b, h, q_row);
// lane = head dim. qkv layout: [B*S, 3*D] rows (q | k | v concatenated).
// Output written in [B, S, D] layout (D index = h*64 + lane) for the
// out-projection GEMM.
// ---------------------------------------------------------------------------
__global__ __launch_bounds__(256)
void attn_causal(const float* __restrict__ qkv, float* __restrict__ out)
{
    const int lane = threadIdx.x & 63;
    const int wave = blockIdx.x * (blockDim.x >> 6) + (threadIdx.x >> 6);
    // wave -> (b, h, q):  bits [15]=b, [14:11]=h, [10:0]=q
    const int q_i = wave & (SEQ - 1);
    const int h = (wave >> 11) & (N_HEADS - 1);
    const int b = wave >> 15;

    const size_t row_stride = QKV_COLS;
    const float* base = qkv + (size_t)b * SEQ * row_stride;
    const int col = h * HEAD_DIM + lane;

    const float qv = base[(size_t)q_i * row_stride + col] * 0.125f; // 1/sqrt(64)
    const float* Kp = base + D_EMBED + col;
    const float* Vp = base + 2 * D_EMBED + col;

    float m = -1e30f, l = 0.f, o = 0.f;
    for (int k = 0; k <= q_i; ++k) {
        float s = qv * Kp[(size_t)k * row_stride];
        // 64-lane reduce-sum (butterfly)
#pragma unroll
        for (int off = 32; off > 0; off >>= 1) s += __shfl_xor(s, off, 64);
        const float m_new = fmaxf(m, s);
        const float scale = __expf(m - m_new);
        const float p = __expf(s - m_new);
        l = l * scale + p;
        o = o * scale + p * Vp[(size_t)k * row_stride];
        m = m_new;
    }
    out[((size_t)(b * SEQ + q_i)) * D_EMBED + col] = o / l;
}

// ---------------------------------------------------------------------------
extern "C" void kernel_launch(void* const* d_in, const int* in_sizes, int n_in,
                              void* d_out, int out_size, void* d_ws, size_t ws_size,
                              hipStream_t stream)
{
    const float* x     = (const float*)d_in[0];   // [B, S, D]
    const float* w_qkv = (const float*)d_in[1];   // [D, 3D]
    const float* b_qkv = (const float*)d_in[2];   // [3D]
    const float* w_o   = (const float*)d_in[3];   // [D, D]
    const float* b_o   = (const float*)d_in[4];   // [D]
    float* out = (float*)d_out;                   // [B, S, D]

    float* qkv  = (float*)d_ws;                            // [ROWS, 3D]  50.3 MB
    float* attn = qkv + (size_t)ROWS * QKV_COLS;           // [ROWS, D]   16.8 MB

    dim3 blk(256);

    // 1) QKV projection: [4096,1024] @ [1024,3072] + b_qkv
    dim3 g1(QKV_COLS / 64, ROWS / 64);
    gemm_bias_f32<<<g1, blk, 0, stream>>>(x, w_qkv, b_qkv, qkv,
                                          ROWS, QKV_COLS, D_EMBED);

    // 2) causal attention: one wave per (b, h, q)
    const int total_waves = BATCH * N_HEADS * SEQ;         // 65536
    attn_causal<<<total_waves / 4, blk, 0, stream>>>(qkv, attn);

    // 3) output projection: [4096,1024] @ [1024,1024] + b_o
    dim3 g2(D_EMBED / 64, ROWS / 64);
    gemm_bias_f32<<<g2, blk, 0, stream>>>(attn, w_o, b_o, out,
                                          ROWS, D_EMBED, D_EMBED);
}

// Round 3
// 1026.001 us; speedup vs baseline: 5.2254x; 5.2254x over previous
//
#include <hip/hip_runtime.h>
#include <hip/hip_bf16.h>

#define D_EMBED 1024
#define N_HEADS 16
#define HEAD_DIM 64
#define BATCH 2
#define SEQ 2048
#define ROWS (BATCH * SEQ)          // 4096
#define QKV_COLS (3 * D_EMBED)      // 3072

// ---------------------------------------------------------------------------
// GEMM: C[M,N] = A[M,K] @ B[K,N] + bias[N]; fp32. 64x64 tile, BK=16,
// 256 threads, 4x4 micro-tile. A staged TRANSPOSED ([k][m]) so the inner
// loop is two ds_read_b128 per 16 FMAs.
// ---------------------------------------------------------------------------
__global__ __launch_bounds__(256)
void gemm_bias_f32(const float* __restrict__ A, const float* __restrict__ B,
                   const float* __restrict__ bias, float* __restrict__ C,
                   int M, int N, int K)
{
    __shared__ float As[16][68];   // [k][m], stride 272B (16B-mult)
    __shared__ float Bs[16][68];   // [k][n]

    const int tid = threadIdx.x;
    const int tx = tid & 15;
    const int ty = tid >> 4;
    const int blockM = blockIdx.y * 64;
    const int blockN = blockIdx.x * 64;

    const int a_row = tid >> 2;          // m   (0..63)
    const int a_k   = (tid & 3) * 4;     // k chunk
    const int b_row = tid >> 4;          // k   (0..15)
    const int b_n   = (tid & 15) * 4;    // n chunk

    float acc[4][4];
#pragma unroll
    for (int i = 0; i < 4; ++i)
#pragma unroll
        for (int j = 0; j < 4; ++j) acc[i][j] = 0.f;

    for (int k0 = 0; k0 < K; k0 += 16) {
        // stage A transposed: [k][m]
        {
            const float4 av = *reinterpret_cast<const float4*>(
                A + (size_t)(blockM + a_row) * K + (k0 + a_k));
            As[a_k + 0][a_row] = av.x;
            As[a_k + 1][a_row] = av.y;
            As[a_k + 2][a_row] = av.z;
            As[a_k + 3][a_row] = av.w;
        }
        // stage B direct: [k][n], vector LDS write
        {
            const float4 bv = *reinterpret_cast<const float4*>(
                B + (size_t)(k0 + b_row) * N + (blockN + b_n));
            *reinterpret_cast<float4*>(&Bs[b_row][b_n]) = bv;
        }
        __syncthreads();

#pragma unroll
        for (int kk = 0; kk < 16; ++kk) {
            const float4 a = *reinterpret_cast<const float4*>(&As[kk][ty * 4]);
            const float4 b = *reinterpret_cast<const float4*>(&Bs[kk][tx * 4]);
            const float ar[4] = {a.x, a.y, a.z, a.w};
            const float br[4] = {b.x, b.y, b.z, b.w};
#pragma unroll
            for (int i = 0; i < 4; ++i)
#pragma unroll
                for (int j = 0; j < 4; ++j) acc[i][j] += ar[i] * br[j];
        }
        __syncthreads();
    }

#pragma unroll
    for (int i = 0; i < 4; ++i) {
        const int row = blockM + ty * 4 + i;
        float4 r;
        r.x = acc[i][0] + bias[blockN + tx * 4 + 0];
        r.y = acc[i][1] + bias[blockN + tx * 4 + 1];
        r.z = acc[i][2] + bias[blockN + tx * 4 + 2];
        r.w = acc[i][3] + bias[blockN + tx * 4 + 3];
        *reinterpret_cast<float4*>(&C[(size_t)row * N + blockN + tx * 4]) = r;
    }
}

// ---------------------------------------------------------------------------
// Flash attention (fp32, causal). One block per (bh, q_tile of 64).
// 256 threads, 4x4 micro-tile. LDS layouts (all [64][64], 16 KB each):
//   Qs[d][q]  (transposed, Q pre-scaled by 1/8)
//   Ks[d][k]  (transposed)
//   Vs[k][d]
//   Ps[k][q]  (transposed; written as float4 along q)
// Inner loops: 2x ds_read_b128 per 16 FMAs; reads are broadcast/2-way.
// ---------------------------------------------------------------------------
__global__ __launch_bounds__(256)
void attn_flash_f32(const float* __restrict__ qkv, float* __restrict__ out)
{
    __shared__ float Qs[64][64];
    __shared__ float Ks[64][64];
    __shared__ float Vs[64][64];
    __shared__ float Ps[64][64];

    const int tid = threadIdx.x;
    const int tx = tid & 15;       // key/dim group
    const int ty = tid >> 4;       // query group
    const int qt = blockIdx.x;     // q tile
    const int bh = blockIdx.y;
    const int b = bh >> 4;
    const int h = bh & 15;
    const int q0 = qt * 64;

    const float* base = qkv + (size_t)b * SEQ * QKV_COLS + h * HEAD_DIM;
    const float* Kbase = base + D_EMBED;
    const float* Vbase = base + 2 * D_EMBED;

    // stage Q transposed, pre-scaled by 1/sqrt(64)
    {
        const int r = tid >> 2;            // q row in tile
        const int c0 = (tid & 3) * 4;      // d chunk
#pragma unroll
        for (int it = 0; it < 4; ++it) {
            const int c = c0 + 16 * it;
            const float4 v = *reinterpret_cast<const float4*>(
                base + (size_t)(q0 + r) * QKV_COLS + c);
            Qs[c + 0][r] = v.x * 0.125f;
            Qs[c + 1][r] = v.y * 0.125f;
            Qs[c + 2][r] = v.z * 0.125f;
            Qs[c + 3][r] = v.w * 0.125f;
        }
    }

    float m_i[4], l_i[4], o[4][4];
#pragma unroll
    for (int i = 0; i < 4; ++i) {
        m_i[i] = -1e30f;
        l_i[i] = 0.f;
#pragma unroll
        for (int j = 0; j < 4; ++j) o[i][j] = 0.f;
    }

    for (int kt = 0; kt <= qt; ++kt) {
        const int k0 = kt * 64;
        __syncthreads();   // previous iter done reading Ks/Vs/Ps; Q visible

        // stage K transposed [d][k]
        {
            const int r = tid >> 2;         // k row
            const int c0 = (tid & 3) * 4;   // d chunk
#pragma unroll
            for (int it = 0; it < 4; ++it) {
                const int c = c0 + 16 * it;
                const float4 v = *reinterpret_cast<const float4*>(
                    Kbase + (size_t)(k0 + r) * QKV_COLS + c);
                Ks[c + 0][r] = v.x;
                Ks[c + 1][r] = v.y;
                Ks[c + 2][r] = v.z;
                Ks[c + 3][r] = v.w;
            }
        }
        // stage V direct [k][d]
        {
            const int c = (tid & 15) * 4;
#pragma unroll
            for (int it = 0; it < 4; ++it) {
                const int r = (tid >> 4) + 16 * it;
                const float4 v = *reinterpret_cast<const float4*>(
                    Vbase + (size_t)(k0 + r) * QKV_COLS + c);
                *reinterpret_cast<float4*>(&Vs[r][c]) = v;
            }
        }
        __syncthreads();

        // GEMM1: s[i][j] = sum_d Qs[d][ty4+i] * Ks[d][tx4+j]
        float s[4][4];
#pragma unroll
        for (int i = 0; i < 4; ++i)
#pragma unroll
            for (int j = 0; j < 4; ++j) s[i][j] = 0.f;

#pragma unroll 8
        for (int d = 0; d < 64; ++d) {
            const float4 a = *reinterpret_cast<const float4*>(&Qs[d][ty * 4]);
            const float4 bb = *reinterpret_cast<const float4*>(&Ks[d][tx * 4]);
            const float ar[4] = {a.x, a.y, a.z, a.w};
            const float br[4] = {bb.x, bb.y, bb.z, bb.w};
#pragma unroll
            for (int i = 0; i < 4; ++i)
#pragma unroll
                for (int j = 0; j < 4; ++j) s[i][j] += ar[i] * br[j];
        }

        // causal mask on the diagonal tile
        if (kt == qt) {
#pragma unroll
            for (int i = 0; i < 4; ++i)
#pragma unroll
                for (int j = 0; j < 4; ++j)
                    if (k0 + tx * 4 + j > q0 + ty * 4 + i) s[i][j] = -1e30f;
        }

        // online softmax (row = 16-lane tx group)
#pragma unroll
        for (int i = 0; i < 4; ++i) {
            float rm = fmaxf(fmaxf(s[i][0], s[i][1]), fmaxf(s[i][2], s[i][3]));
#pragma unroll
            for (int off = 1; off < 16; off <<= 1)
                rm = fmaxf(rm, __shfl_xor(rm, off, 64));
            const float mn = fmaxf(m_i[i], rm);
            const float alpha = __expf(m_i[i] - mn);
            float rs = 0.f;
#pragma unroll
            for (int j = 0; j < 4; ++j) {
                s[i][j] = __expf(s[i][j] - mn);
                rs += s[i][j];
            }
#pragma unroll
            for (int off = 1; off < 16; off <<= 1)
                rs += __shfl_xor(rs, off, 64);
            l_i[i] = l_i[i] * alpha + rs;
            m_i[i] = mn;
#pragma unroll
            for (int j = 0; j < 4; ++j) o[i][j] *= alpha;
        }

        // write P transposed [k][q], float4 along q
        __syncthreads();   // all waves done reading Ps from previous GEMM2
#pragma unroll
        for (int j = 0; j < 4; ++j) {
            float4 p4;
            p4.x = s[0][j]; p4.y = s[1][j]; p4.z = s[2][j]; p4.w = s[3][j];
            *reinterpret_cast<float4*>(&Ps[tx * 4 + j][ty * 4]) = p4;
        }
        __syncthreads();

        // GEMM2: o[i][j] += sum_k Ps[k][ty4+i] * Vs[k][tx4+j]
#pragma unroll 8
        for (int k = 0; k < 64; ++k) {
            const float4 a = *reinterpret_cast<const float4*>(&Ps[k][ty * 4]);
            const float4 bb = *reinterpret_cast<const float4*>(&Vs[k][tx * 4]);
            const float ar[4] = {a.x, a.y, a.z, a.w};
            const float br[4] = {bb.x, bb.y, bb.z, bb.w};
#pragma unroll
            for (int i = 0; i < 4; ++i)
#pragma unroll
                for (int j = 0; j < 4; ++j) o[i][j] += ar[i] * br[j];
        }
    }

    // epilogue: out[b, q, h*64+d] = o / l
#pragma unroll
    for (int i = 0; i < 4; ++i) {
        const int row = q0 + ty * 4 + i;
        const float inv_l = 1.f / l_i[i];
        float4 r;
        r.x = o[i][0] * inv_l;
        r.y = o[i][1] * inv_l;
        r.z = o[i][2] * inv_l;
        r.w = o[i][3] * inv_l;
        *reinterpret_cast<float4*>(
            &out[((size_t)(b * SEQ + row)) * D_EMBED + h * HEAD_DIM + tx * 4]) = r;
    }
}

// ---------------------------------------------------------------------------
extern "C" void kernel_launch(void* const* d_in, const int* in_sizes, int n_in,
                              void* d_out, int out_size, void* d_ws, size_t ws_size,
                              hipStream_t stream)
{
    const float* x     = (const float*)d_in[0];   // [B, S, D]
    const float* w_qkv = (const float*)d_in[1];   // [D, 3D]
    const float* b_qkv = (const float*)d_in[2];   // [3D]
    const float* w_o   = (const float*)d_in[3];   // [D, D]
    const float* b_o   = (const float*)d_in[4];   // [D]
    float* out = (float*)d_out;                   // [B, S, D]

    float* qkv  = (float*)d_ws;                            // [ROWS, 3D]
    float* attn = qkv + (size_t)ROWS * QKV_COLS;           // [ROWS, D]

    dim3 blk(256);

    // 1) QKV projection
    dim3 g1(QKV_COLS / 64, ROWS / 64);
    gemm_bias_f32<<<g1, blk, 0, stream>>>(x, w_qkv, b_qkv, qkv,
                                          ROWS, QKV_COLS, D_EMBED);

    // 2) flash attention: block per (q_tile, b*h)
    dim3 g2(SEQ / 64, BATCH * N_HEADS);
    attn_flash_f32<<<g2, blk, 0, stream>>>(qkv, attn);

    // 3) output projection
    dim3 g3(D_EMBED / 64, ROWS / 64);
    gemm_bias_f32<<<g3, blk, 0, stream>>>(attn, w_o, b_o, out,
                                          ROWS, D_EMBED, D_EMBED);
}

// Round 4
// 244.215 us; speedup vs baseline: 21.9529x; 4.2012x over previous
//
#include <hip/hip_runtime.h>
#include <hip/hip_bf16.h>

typedef __hip_bfloat16 bf16;
typedef unsigned short u16;
typedef __attribute__((ext_vector_type(8))) short short8;
typedef __attribute__((ext_vector_type(4))) float floatx4;

#define D_EMBED 1024
#define N_HEADS 16
#define HEAD_DIM 64
#define BATCH 2
#define SEQ 2048
#define ROWS (BATCH * SEQ)          // 4096
#define QKV_COLS (3 * D_EMBED)      // 3072

__device__ __forceinline__ void g2l16(const void* g, void* l) {
    __builtin_amdgcn_global_load_lds(
        (const __attribute__((address_space(1))) unsigned int*)g,
        (__attribute__((address_space(3))) unsigned int*)l,
        16, 0, 0);
}

__device__ __forceinline__ u16 f2b_bits(float f) {
    bf16 h = __float2bfloat16(f);
    u16 u;
    __builtin_memcpy(&u, &h, 2);
    return u;
}

__device__ __forceinline__ unsigned pack2(float a, float b) {
    return (unsigned)f2b_bits(a) | ((unsigned)f2b_bits(b) << 16);
}

// ---------------------------------------------------------------------------
// elementwise fp32 -> bf16 cast (x). n4 = number of float4 groups.
// ---------------------------------------------------------------------------
__global__ __launch_bounds__(256)
void cast_bf16(const float* __restrict__ in, bf16* __restrict__ out)
{
    const int i = blockIdx.x * 256 + threadIdx.x;
    const float4 v = reinterpret_cast<const float4*>(in)[i];
    ushort4 o;
    o.x = f2b_bits(v.x); o.y = f2b_bits(v.y);
    o.z = f2b_bits(v.z); o.w = f2b_bits(v.w);
    reinterpret_cast<ushort4*>(out)[i] = o;
}

// ---------------------------------------------------------------------------
// transpose + cast: in fp32 [R][C] -> out bf16 [C][R]. 64x64 tiles.
// ---------------------------------------------------------------------------
__global__ __launch_bounds__(256)
void tcast_bf16(const float* __restrict__ in, bf16* __restrict__ out, int R, int C)
{
    __shared__ u16 T[64][72];
    const int tid = threadIdx.x;
    const int r0 = blockIdx.y * 64, c0 = blockIdx.x * 64;
#pragma unroll
    for (int it = 0; it < 4; ++it) {
        const int r = (tid >> 4) + it * 16;
        const int c4 = (tid & 15) * 4;
        const float4 v = *reinterpret_cast<const float4*>(in + (size_t)(r0 + r) * C + c0 + c4);
        T[c4 + 0][r] = f2b_bits(v.x);
        T[c4 + 1][r] = f2b_bits(v.y);
        T[c4 + 2][r] = f2b_bits(v.z);
        T[c4 + 3][r] = f2b_bits(v.w);
    }
    __syncthreads();
#pragma unroll
    for (int it = 0; it < 4; ++it) {
        const int rr = (tid >> 4) + it * 16;   // output row (c dim)
        const int cc4 = (tid & 15) * 4;        // output col (r dim)
        ushort4 o = *reinterpret_cast<const ushort4*>(&T[rr][cc4]);
        *reinterpret_cast<ushort4*>(
            reinterpret_cast<u16*>(out) + (size_t)(c0 + rr) * R + r0 + cc4) = o;
    }
}

// ---------------------------------------------------------------------------
// MFMA GEMM, m97 structure: C[M,N] = A[M,1024] @ Bt[N,1024]^T + bias.
// 128x128 tile, BK=32, 256 threads (4 waves in 2x2), 16x16x32 bf16 MFMA.
// mode 0: QKV epilogue -> qb/kb row-major bf16, V scattered transposed to vtb.
// mode 1: fp32 out + bias.
// ---------------------------------------------------------------------------
__global__ __launch_bounds__(256)
void gemm_mfma(const bf16* __restrict__ A, const bf16* __restrict__ Bt,
               const float* __restrict__ bias, int mode,
               bf16* __restrict__ qb, bf16* __restrict__ kb,
               bf16* __restrict__ vtb, float* __restrict__ outf)
{
    __shared__ __align__(16) char smem[16384];
    char* As = smem;            // [128 m][32 k] bf16, 64B rows
    char* Bs = smem + 8192;     // [128 n][32 k]

    const int tid = threadIdx.x;
    const int lane = tid & 63, w = tid >> 6;
    const int quad = lane >> 4, l15 = lane & 15;
    const int mw = (w >> 1) * 64, nw = (w & 1) * 64;
    const int blockM = blockIdx.y * 128, blockN = blockIdx.x * 128;

    floatx4 acc[4][4];
#pragma unroll
    for (int i = 0; i < 4; ++i)
#pragma unroll
        for (int j = 0; j < 4; ++j) acc[i][j] = (floatx4){0.f, 0.f, 0.f, 0.f};

    for (int k0 = 0; k0 < 1024; k0 += 32) {
        __syncthreads();
#pragma unroll
        for (int it = 0; it < 2; ++it) {
            const int p = it * 256 + tid;
            const int row = p >> 2, ch = p & 3;
            char* dst = As + (it * 256 + (tid & ~63)) * 16;
            g2l16(A + (size_t)(blockM + row) * 1024 + k0 + ch * 8, dst);
            g2l16(Bt + (size_t)(blockN + row) * 1024 + k0 + ch * 8, dst + 8192);
        }
        __syncthreads();

        short8 af[4], bfr[4];
#pragma unroll
        for (int mi = 0; mi < 4; ++mi)
            af[mi] = *reinterpret_cast<const short8*>(
                As + (mw + mi * 16 + l15) * 64 + quad * 16);
#pragma unroll
        for (int ni = 0; ni < 4; ++ni)
            bfr[ni] = *reinterpret_cast<const short8*>(
                Bs + (nw + ni * 16 + l15) * 64 + quad * 16);
#pragma unroll
        for (int mi = 0; mi < 4; ++mi)
#pragma unroll
            for (int ni = 0; ni < 4; ++ni)
                acc[mi][ni] = __builtin_amdgcn_mfma_f32_16x16x32_bf16(
                    af[mi], bfr[ni], acc[mi][ni], 0, 0, 0);
    }

    // epilogue
    if (mode == 0) {
        const bool isv = (blockN >= 2048);
        const bool isq = (blockN < 1024);
#pragma unroll
        for (int mi = 0; mi < 4; ++mi)
#pragma unroll
            for (int r = 0; r < 4; ++r) {
                const int row = blockM + mw + mi * 16 + quad * 4 + r;
#pragma unroll
                for (int ni = 0; ni < 4; ++ni) {
                    const int col = blockN + nw + ni * 16 + l15;
                    const bf16 bv = __float2bfloat16(acc[mi][ni][r] + bias[col]);
                    if (isq) {
                        qb[(size_t)row * 1024 + col] = bv;
                    } else if (!isv) {
                        kb[(size_t)row * 1024 + col - 1024] = bv;
                    } else {
                        const int c = col - 2048;
                        const int bh = (row >> 11) * 16 + (c >> 6);
                        vtb[(size_t)(bh * 64 + (c & 63)) * SEQ + (row & 2047)] = bv;
                    }
                }
            }
    } else {
#pragma unroll
        for (int mi = 0; mi < 4; ++mi)
#pragma unroll
            for (int r = 0; r < 4; ++r) {
                const int row = blockM + mw + mi * 16 + quad * 4 + r;
#pragma unroll
                for (int ni = 0; ni < 4; ++ni) {
                    const int col = blockN + nw + ni * 16 + l15;
                    outf[(size_t)row * 1024 + col] = acc[mi][ni][r] + bias[col];
                }
            }
    }
}

// ---------------------------------------------------------------------------
// MFMA flash attention (causal). Block = (q-tile 64, bh). 4 waves; each wave
// owns 16 q columns (n = lane&15) and the full 64-k_s tile.
//   S^T = K·Q^T  (m=k_s, n=q, k=d)  -> C-layout: k_s=quad*4+reg, q=lane&15
//   softmax rows (q) reduce with 2 cross-quad shuffles
//   P: C-layout -> per-wave LDS [q][k] (16B-column-major) -> B-fragment
//   O^T += V^T·P (m=d, n=q, k=k_s); V pre-transposed in vtb.
// LDS tiles XOR-8 swizzled at 16B granularity -> conflict-free b128 reads.
// ---------------------------------------------------------------------------
__global__ __launch_bounds__(256)
void attn_mfma(const bf16* __restrict__ qb, const bf16* __restrict__ kb,
               const bf16* __restrict__ vtb, bf16* __restrict__ ob)
{
    __shared__ __align__(16) char smem[32768];
    char* Qs = smem;            // [64 q][64 d], swizzled
    char* Ks = smem + 8192;     // [64 s][64 d], swizzled
    char* Vs = smem + 16384;    // [64 d][64 s], swizzled
    const int tid = threadIdx.x;
    const int lane = tid & 63, w = tid >> 6;
    const int quad = lane >> 4, l15 = lane & 15;
    char* Ps = smem + 24576 + w * 2048;   // per-wave [16 q][64 k] col-major-16B

    const int qt = blockIdx.x, bh = blockIdx.y;
    const int b = bh >> 4, h = bh & 15;
    const int q0 = qt * 64;
    const int qrow = q0 + w * 16 + l15;

    // stage Q tile
#pragma unroll
    for (int it = 0; it < 2; ++it) {
        const int p = it * 256 + tid;
        const int row = p >> 3;
        const int lch = (p & 7) ^ (row & 7);
        g2l16(qb + (size_t)(b * SEQ + q0 + row) * D_EMBED + h * 64 + lch * 8,
              Qs + (it * 256 + (tid & ~63)) * 16);
    }

    floatx4 Oacc[4];
#pragma unroll
    for (int i = 0; i < 4; ++i) Oacc[i] = (floatx4){0.f, 0.f, 0.f, 0.f};
    float m_i = -1e30f, l_i = 0.f;

    for (int kt = 0; kt <= qt; ++kt) {
        const int k0 = kt * 64;
        __syncthreads();    // prev iter done reading Ks/Vs
#pragma unroll
        for (int it = 0; it < 2; ++it) {
            const int p = it * 256 + tid;
            const int row = p >> 3;
            const int lch = (p & 7) ^ (row & 7);
            char* dst = Ks + (it * 256 + (tid & ~63)) * 16;
            g2l16(kb + (size_t)(b * SEQ + k0 + row) * D_EMBED + h * 64 + lch * 8, dst);
            g2l16(vtb + (size_t)(bh * 64 + row) * SEQ + k0 + lch * 8, dst + 8192);
        }
        __syncthreads();    // staged data visible (vmcnt drained at barrier)

        // S^T = K · Q^T
        short8 qf0 = *reinterpret_cast<const short8*>(
            Qs + (w * 16 + l15) * 128 + ((quad ^ (l15 & 7)) * 16));
        short8 qf1 = *reinterpret_cast<const short8*>(
            Qs + (w * 16 + l15) * 128 + (((quad + 4) ^ (l15 & 7)) * 16));
        floatx4 Sacc[4];
#pragma unroll
        for (int ms = 0; ms < 4; ++ms) {
            Sacc[ms] = (floatx4){0.f, 0.f, 0.f, 0.f};
            short8 kf0 = *reinterpret_cast<const short8*>(
                Ks + (ms * 16 + l15) * 128 + ((quad ^ (l15 & 7)) * 16));
            Sacc[ms] = __builtin_amdgcn_mfma_f32_16x16x32_bf16(kf0, qf0, Sacc[ms], 0, 0, 0);
            short8 kf1 = *reinterpret_cast<const short8*>(
                Ks + (ms * 16 + l15) * 128 + (((quad + 4) ^ (l15 & 7)) * 16));
            Sacc[ms] = __builtin_amdgcn_mfma_f32_16x16x32_bf16(kf1, qf1, Sacc[ms], 0, 0, 0);
        }

        // scale + causal mask + online softmax (row = this lane's q)
        float sv[4][4];
        float rowmax = -1e30f;
        const bool diag = (kt == qt);
#pragma unroll
        for (int ms = 0; ms < 4; ++ms)
#pragma unroll
            for (int r = 0; r < 4; ++r) {
                float s = Sacc[ms][r] * 0.125f;
                if (diag && (k0 + ms * 16 + quad * 4 + r) > qrow) s = -1e30f;
                sv[ms][r] = s;
                rowmax = fmaxf(rowmax, s);
            }
        rowmax = fmaxf(rowmax, __shfl_xor(rowmax, 16, 64));
        rowmax = fmaxf(rowmax, __shfl_xor(rowmax, 32, 64));
        const float mnew = fmaxf(m_i, rowmax);
        const float alpha = __expf(m_i - mnew);
        float psum = 0.f;
#pragma unroll
        for (int ms = 0; ms < 4; ++ms) {
            const float p0 = __expf(sv[ms][0] - mnew);
            const float p1 = __expf(sv[ms][1] - mnew);
            const float p2 = __expf(sv[ms][2] - mnew);
            const float p3 = __expf(sv[ms][3] - mnew);
            psum += (p0 + p1) + (p2 + p3);
            const int k = ms * 16 + quad * 4;
            *reinterpret_cast<unsigned*>(
                Ps + (k >> 3) * 256 + l15 * 16 + (k & 7) * 2) = pack2(p0, p1);
            *reinterpret_cast<unsigned*>(
                Ps + ((k + 2) >> 3) * 256 + l15 * 16 + ((k + 2) & 7) * 2) = pack2(p2, p3);
        }
        psum += __shfl_xor(psum, 16, 64);
        psum += __shfl_xor(psum, 32, 64);
        l_i = l_i * alpha + psum;
        m_i = mnew;
#pragma unroll
        for (int ds = 0; ds < 4; ++ds) {
            Oacc[ds][0] *= alpha; Oacc[ds][1] *= alpha;
            Oacc[ds][2] *= alpha; Oacc[ds][3] *= alpha;
        }

        // O^T += V^T · P
#pragma unroll
        for (int ks = 0; ks < 2; ++ks) {
            short8 pf = *reinterpret_cast<const short8*>(
                Ps + (ks * 4 + quad) * 256 + l15 * 16);
#pragma unroll
            for (int ds = 0; ds < 4; ++ds) {
                short8 vf = *reinterpret_cast<const short8*>(
                    Vs + (ds * 16 + l15) * 128 + (((quad + ks * 4) ^ (l15 & 7)) * 16));
                Oacc[ds] = __builtin_amdgcn_mfma_f32_16x16x32_bf16(vf, pf, Oacc[ds], 0, 0, 0);
            }
        }
    }

    // epilogue: O^T -> per-wave LDS [q][d] -> coalesced 16B stores
    const float invl = 1.f / l_i;
#pragma unroll
    for (int ds = 0; ds < 4; ++ds) {
        const int d = ds * 16 + quad * 4;
        *reinterpret_cast<unsigned*>(
            Ps + (d >> 3) * 256 + l15 * 16 + (d & 7) * 2) =
            pack2(Oacc[ds][0] * invl, Oacc[ds][1] * invl);
        *reinterpret_cast<unsigned*>(
            Ps + ((d + 2) >> 3) * 256 + l15 * 16 + ((d + 2) & 7) * 2) =
            pack2(Oacc[ds][2] * invl, Oacc[ds][3] * invl);
    }
#pragma unroll
    for (int it = 0; it < 2; ++it) {
        const int idx = it * 64 + lane;
        const int ch = idx >> 4, q = idx & 15;
        short8 ov = *reinterpret_cast<const short8*>(Ps + ch * 256 + q * 16);
        *reinterpret_cast<short8*>(
            ob + (size_t)(b * SEQ + q0 + w * 16 + q) * D_EMBED + h * 64 + ch * 8) = ov;
    }
}

// ---------------------------------------------------------------------------
extern "C" void kernel_launch(void* const* d_in, const int* in_sizes, int n_in,
                              void* d_out, int out_size, void* d_ws, size_t ws_size,
                              hipStream_t stream)
{
    const float* x     = (const float*)d_in[0];   // [4096, 1024]
    const float* w_qkv = (const float*)d_in[1];   // [1024, 3072]
    const float* b_qkv = (const float*)d_in[2];   // [3072]
    const float* w_o   = (const float*)d_in[3];   // [1024, 1024]
    const float* b_o   = (const float*)d_in[4];   // [1024]
    float* out = (float*)d_out;                   // [4096, 1024] fp32

    bf16* xb     = (bf16*)d_ws;                    // [4096][1024]
    bf16* wqkvT  = xb + (size_t)4096 * 1024;       // [3072][1024]
    bf16* woT    = wqkvT + (size_t)3072 * 1024;    // [1024][1024]
    bf16* qbuf   = woT + (size_t)1024 * 1024;      // [4096][1024]
    bf16* kbuf   = qbuf + (size_t)4096 * 1024;     // [4096][1024]
    bf16* vtb    = kbuf + (size_t)4096 * 1024;     // [32 bh][64 d][2048 s]
    bf16* attnb  = vtb + (size_t)4096 * 1024;      // [4096][1024]

    dim3 blk(256);

    // casts
    cast_bf16<<<dim3(4096), blk, 0, stream>>>(x, xb);
    tcast_bf16<<<dim3(48, 16), blk, 0, stream>>>(w_qkv, wqkvT, 1024, 3072);
    tcast_bf16<<<dim3(16, 16), blk, 0, stream>>>(w_o, woT, 1024, 1024);

    // QKV projection (writes qbuf, kbuf, vtb transposed)
    gemm_mfma<<<dim3(24, 32), blk, 0, stream>>>(xb, wqkvT, b_qkv, 0,
                                                qbuf, kbuf, vtb, (float*)nullptr);

    // flash attention
    attn_mfma<<<dim3(32, 32), blk, 0, stream>>>(qbuf, kbuf, vtb, attnb);

    // output projection (fp32 out + bias)
    gemm_mfma<<<dim3(8, 32), blk, 0, stream>>>(attnb, woT, b_o, 1,
                                               (bf16*)nullptr, (bf16*)nullptr,
                                               (bf16*)nullptr, out);
}

// Round 5
// 220.671 us; speedup vs baseline: 24.2952x; 1.1067x over previous
//
#include <hip/hip_runtime.h>
#include <hip/hip_bf16.h>

typedef __hip_bfloat16 bf16;
typedef unsigned short u16;
typedef __attribute__((ext_vector_type(8))) short short8;
typedef __attribute__((ext_vector_type(4))) float floatx4;

#define D_EMBED 1024
#define N_HEADS 16
#define HEAD_DIM 64
#define BATCH 2
#define SEQ 2048
#define ROWS (BATCH * SEQ)          // 4096
#define QKV_COLS (3 * D_EMBED)      // 3072
// exp2-domain scale folded into Q: log2(e)/sqrt(64)
#define QSCALE 0.1803368801f

__device__ __forceinline__ void g2l16(const void* g, void* l) {
    __builtin_amdgcn_global_load_lds(
        (const __attribute__((address_space(1))) unsigned int*)g,
        (__attribute__((address_space(3))) unsigned int*)l,
        16, 0, 0);
}

__device__ __forceinline__ u16 f2b_bits(float f) {
    bf16 h = __float2bfloat16(f);
    u16 u;
    __builtin_memcpy(&u, &h, 2);
    return u;
}

__device__ __forceinline__ unsigned pack2(float a, float b) {   // RNE pack
    return (unsigned)f2b_bits(a) | ((unsigned)f2b_bits(b) << 16);
}

__device__ __forceinline__ float fexp2(float x) {
#if __has_builtin(__builtin_amdgcn_exp2f)
    return __builtin_amdgcn_exp2f(x);
#else
    return exp2f(x);
#endif
}

// pack two fp32 -> two truncated bf16 in one op (low = a, high = b)
__device__ __forceinline__ unsigned permpack(float a, float b) {
#if __has_builtin(__builtin_amdgcn_perm)
    return __builtin_amdgcn_perm(__float_as_uint(b), __float_as_uint(a), 0x07060302u);
#else
    return (__float_as_uint(a) >> 16) | (__float_as_uint(b) & 0xFFFF0000u);
#endif
}

// ---------------------------------------------------------------------------
// elementwise fp32 -> bf16 cast (x).
// ---------------------------------------------------------------------------
__global__ __launch_bounds__(256)
void cast_bf16(const float* __restrict__ in, bf16* __restrict__ out)
{
    const int i = blockIdx.x * 256 + threadIdx.x;
    const float4 v = reinterpret_cast<const float4*>(in)[i];
    ushort4 o;
    o.x = f2b_bits(v.x); o.y = f2b_bits(v.y);
    o.z = f2b_bits(v.z); o.w = f2b_bits(v.w);
    reinterpret_cast<ushort4*>(out)[i] = o;
}

// ---------------------------------------------------------------------------
// transpose + cast: in fp32 [R][C] -> out bf16 [C][R]. 64x64 tiles.
// ---------------------------------------------------------------------------
__global__ __launch_bounds__(256)
void tcast_bf16(const float* __restrict__ in, bf16* __restrict__ out, int R, int C)
{
    __shared__ u16 T[64][72];
    const int tid = threadIdx.x;
    const int r0 = blockIdx.y * 64, c0 = blockIdx.x * 64;
#pragma unroll
    for (int it = 0; it < 4; ++it) {
        const int r = (tid >> 4) + it * 16;
        const int c4 = (tid & 15) * 4;
        const float4 v = *reinterpret_cast<const float4*>(in + (size_t)(r0 + r) * C + c0 + c4);
        T[c4 + 0][r] = f2b_bits(v.x);
        T[c4 + 1][r] = f2b_bits(v.y);
        T[c4 + 2][r] = f2b_bits(v.z);
        T[c4 + 3][r] = f2b_bits(v.w);
    }
    __syncthreads();
#pragma unroll
    for (int it = 0; it < 4; ++it) {
        const int rr = (tid >> 4) + it * 16;
        const int cc4 = (tid & 15) * 4;
        ushort4 o = *reinterpret_cast<const ushort4*>(&T[rr][cc4]);
        *reinterpret_cast<ushort4*>(
            reinterpret_cast<u16*>(out) + (size_t)(c0 + rr) * R + r0 + cc4) = o;
    }
}

// ---------------------------------------------------------------------------
// bf16 transpose: vb [B*S][1024] (per-head 64 cols) -> vtb [bh*64+d][S].
// 64(s) x 64(d) tiles through LDS; 16B loads and stores.
// ---------------------------------------------------------------------------
__global__ __launch_bounds__(256)
void vtrans(const bf16* __restrict__ vb, bf16* __restrict__ vtb)
{
    __shared__ __align__(16) u16 T[64][72];   // [s][d], 144B rows (16B-mult)
    const int tid = threadIdx.x;
    const int s0 = blockIdx.x * 64;
    const int bh = blockIdx.y;
    const int b = bh >> 4, h = bh & 15;
    const u16* src = reinterpret_cast<const u16*>(vb) +
                     (size_t)(b * SEQ + s0) * D_EMBED + h * 64;
    u16* dst = reinterpret_cast<u16*>(vtb) + (size_t)bh * 64 * SEQ + s0;

#pragma unroll
    for (int it = 0; it < 2; ++it) {
        const int idx = it * 256 + tid;
        const int sr = idx >> 3, ch = idx & 7;
        const short8 v = *reinterpret_cast<const short8*>(src + (size_t)sr * D_EMBED + ch * 8);
        *reinterpret_cast<short8*>(&T[sr][ch * 8]) = v;
    }
    __syncthreads();
#pragma unroll
    for (int it = 0; it < 2; ++it) {
        const int idx = it * 256 + tid;
        const int d = idx >> 3, sc = idx & 7;
        u16 tmp[8];
#pragma unroll
        for (int e = 0; e < 8; ++e) tmp[e] = T[sc * 8 + e][d];
        *reinterpret_cast<short8*>(dst + (size_t)d * SEQ + sc * 8) =
            *reinterpret_cast<const short8*>(tmp);
    }
}

// ---------------------------------------------------------------------------
// MFMA GEMM, m97 structure: C[M,N] = A[M,1024] @ Bt[N,1024]^T + bias.
// 128x128 tile, BK=32, 256 threads (4 waves 2x2), 16x16x32 bf16 MFMA.
// mode 0: QKV epilogue -> qb (scaled by QSCALE), kb, vb row-major bf16.
// mode 1: fp32 out + bias.
// ---------------------------------------------------------------------------
__global__ __launch_bounds__(256)
void gemm_mfma(const bf16* __restrict__ A, const bf16* __restrict__ Bt,
               const float* __restrict__ bias, int mode,
               bf16* __restrict__ qb, bf16* __restrict__ kb,
               bf16* __restrict__ vb, float* __restrict__ outf)
{
    __shared__ __align__(16) char smem[16384];
    char* As = smem;            // [128 m][32 k] bf16, 64B rows
    char* Bs = smem + 8192;     // [128 n][32 k]

    const int tid = threadIdx.x;
    const int lane = tid & 63, w = tid >> 6;
    const int quad = lane >> 4, l15 = lane & 15;
    const int mw = (w >> 1) * 64, nw = (w & 1) * 64;
    const int blockM = blockIdx.y * 128, blockN = blockIdx.x * 128;

    floatx4 acc[4][4];
#pragma unroll
    for (int i = 0; i < 4; ++i)
#pragma unroll
        for (int j = 0; j < 4; ++j) acc[i][j] = (floatx4){0.f, 0.f, 0.f, 0.f};

    for (int k0 = 0; k0 < 1024; k0 += 32) {
        __syncthreads();
#pragma unroll
        for (int it = 0; it < 2; ++it) {
            const int p = it * 256 + tid;
            const int row = p >> 2, ch = p & 3;
            char* dst = As + (it * 256 + (tid & ~63)) * 16;
            g2l16(A + (size_t)(blockM + row) * 1024 + k0 + ch * 8, dst);
            g2l16(Bt + (size_t)(blockN + row) * 1024 + k0 + ch * 8, dst + 8192);
        }
        __syncthreads();

        short8 af[4], bfr[4];
#pragma unroll
        for (int mi = 0; mi < 4; ++mi)
            af[mi] = *reinterpret_cast<const short8*>(
                As + (mw + mi * 16 + l15) * 64 + quad * 16);
#pragma unroll
        for (int ni = 0; ni < 4; ++ni)
            bfr[ni] = *reinterpret_cast<const short8*>(
                Bs + (nw + ni * 16 + l15) * 64 + quad * 16);
#pragma unroll
        for (int mi = 0; mi < 4; ++mi)
#pragma unroll
            for (int ni = 0; ni < 4; ++ni)
                acc[mi][ni] = __builtin_amdgcn_mfma_f32_16x16x32_bf16(
                    af[mi], bfr[ni], acc[mi][ni], 0, 0, 0);
    }

    if (mode == 0) {
        const bool isv = (blockN >= 2048);
        const bool isq = (blockN < 1024);
#pragma unroll
        for (int mi = 0; mi < 4; ++mi)
#pragma unroll
            for (int r = 0; r < 4; ++r) {
                const int row = blockM + mw + mi * 16 + quad * 4 + r;
#pragma unroll
                for (int ni = 0; ni < 4; ++ni) {
                    const int col = blockN + nw + ni * 16 + l15;
                    float val = acc[mi][ni][r] + bias[col];
                    if (isq) val *= QSCALE;        // exp2-domain attn scale
                    const bf16 bv = __float2bfloat16(val);
                    if (isq) {
                        qb[(size_t)row * 1024 + col] = bv;
                    } else if (!isv) {
                        kb[(size_t)row * 1024 + col - 1024] = bv;
                    } else {
                        vb[(size_t)row * 1024 + col - 2048] = bv;
                    }
                }
            }
    } else {
#pragma unroll
        for (int mi = 0; mi < 4; ++mi)
#pragma unroll
            for (int r = 0; r < 4; ++r) {
                const int row = blockM + mw + mi * 16 + quad * 4 + r;
#pragma unroll
                for (int ni = 0; ni < 4; ++ni) {
                    const int col = blockN + nw + ni * 16 + l15;
                    outf[(size_t)row * 1024 + col] = acc[mi][ni][r] + bias[col];
                }
            }
    }
}

// ---------------------------------------------------------------------------
// MFMA flash attention (causal), max-free exp2-domain softmax.
//   S^T = K·Q^T (Q pre-scaled by QSCALE)  -> C-layout: k_s=quad*4+r, q=l15
//   P = exp2(S^T) elementwise (no max subtraction: |S| <~ 5, fp32-safe)
//   l = ones-row MFMA column-sum of P (matrix pipe, not VALU)
//   O^T += V^T·P ; epilogue scales by 1/l.
// qt reversed so the longest causal blocks are dispatched first.
// ---------------------------------------------------------------------------
__global__ __launch_bounds__(256)
void attn_mfma(const bf16* __restrict__ qb, const bf16* __restrict__ kb,
               const bf16* __restrict__ vtb, bf16* __restrict__ ob)
{
    __shared__ __align__(16) char smem[32768];
    char* Qs = smem;            // [64 q][64 d], swizzled
    char* Ks = smem + 8192;     // [64 s][64 d], swizzled
    char* Vs = smem + 16384;    // [64 d][64 s], swizzled
    const int tid = threadIdx.x;
    const int lane = tid & 63, w = tid >> 6;
    const int quad = lane >> 4, l15 = lane & 15;
    char* Ps = smem + 24576 + w * 2048;   // per-wave [8 kchunk][16 q][16B]

    const int qt = gridDim.x - 1 - blockIdx.x;   // heavy blocks first
    const int bh = blockIdx.y;
    const int b = bh >> 4, h = bh & 15;
    const int q0 = qt * 64;
    const int qrow = q0 + w * 16 + l15;

    // stage Q tile
#pragma unroll
    for (int it = 0; it < 2; ++it) {
        const int p = it * 256 + tid;
        const int row = p >> 3;
        const int lch = (p & 7) ^ (row & 7);
        g2l16(qb + (size_t)(b * SEQ + q0 + row) * D_EMBED + h * 64 + lch * 8,
              Qs + (it * 256 + (tid & ~63)) * 16);
    }

    floatx4 Oacc[4], Lacc;
#pragma unroll
    for (int i = 0; i < 4; ++i) Oacc[i] = (floatx4){0.f, 0.f, 0.f, 0.f};
    Lacc = (floatx4){0.f, 0.f, 0.f, 0.f};

    const short8 ones = {0x3F80, 0x3F80, 0x3F80, 0x3F80,
                         0x3F80, 0x3F80, 0x3F80, 0x3F80};   // bf16 1.0 x8

    for (int kt = 0; kt <= qt; ++kt) {
        const int k0 = kt * 64;
        __syncthreads();
#pragma unroll
        for (int it = 0; it < 2; ++it) {
            const int p = it * 256 + tid;
            const int row = p >> 3;
            const int lch = (p & 7) ^ (row & 7);
            char* dst = Ks + (it * 256 + (tid & ~63)) * 16;
            g2l16(kb + (size_t)(b * SEQ + k0 + row) * D_EMBED + h * 64 + lch * 8, dst);
            g2l16(vtb + (size_t)(bh * 64 + row) * SEQ + k0 + lch * 8, dst + 8192);
        }
        __syncthreads();

        // S^T = K · Q^T
        short8 qf0 = *reinterpret_cast<const short8*>(
            Qs + (w * 16 + l15) * 128 + ((quad ^ (l15 & 7)) * 16));
        short8 qf1 = *reinterpret_cast<const short8*>(
            Qs + (w * 16 + l15) * 128 + (((quad + 4) ^ (l15 & 7)) * 16));
        floatx4 Sacc[4];
#pragma unroll
        for (int ms = 0; ms < 4; ++ms) {
            Sacc[ms] = (floatx4){0.f, 0.f, 0.f, 0.f};
            short8 kf0 = *reinterpret_cast<const short8*>(
                Ks + (ms * 16 + l15) * 128 + ((quad ^ (l15 & 7)) * 16));
            Sacc[ms] = __builtin_amdgcn_mfma_f32_16x16x32_bf16(kf0, qf0, Sacc[ms], 0, 0, 0);
            short8 kf1 = *reinterpret_cast<const short8*>(
                Ks + (ms * 16 + l15) * 128 + (((quad + 4) ^ (l15 & 7)) * 16));
            Sacc[ms] = __builtin_amdgcn_mfma_f32_16x16x32_bf16(kf1, qf1, Sacc[ms], 0, 0, 0);
        }

        // P = exp2(S^T) (+ causal mask on diagonal tile), write to LDS
        const bool diag = (kt == qt);
#pragma unroll
        for (int ms = 0; ms < 4; ++ms) {
            float p[4];
#pragma unroll
            for (int r = 0; r < 4; ++r) {
                float s = Sacc[ms][r];
                if (diag && (k0 + ms * 16 + quad * 4 + r) > qrow) s = -1e30f;
                p[r] = fexp2(s);
            }
            const int k = ms * 16 + quad * 4;
            uint2 pw;
            pw.x = permpack(p[0], p[1]);
            pw.y = permpack(p[2], p[3]);
            *reinterpret_cast<uint2*>(Ps + (k >> 3) * 256 + l15 * 16 + (k & 7) * 2) = pw;
        }

        // l += 1^T·P (matrix pipe);  O^T += V^T·P
#pragma unroll
        for (int ks = 0; ks < 2; ++ks) {
            short8 pf = *reinterpret_cast<const short8*>(
                Ps + (ks * 4 + quad) * 256 + l15 * 16);
            Lacc = __builtin_amdgcn_mfma_f32_16x16x32_bf16(ones, pf, Lacc, 0, 0, 0);
#pragma unroll
            for (int ds = 0; ds < 4; ++ds) {
                short8 vf = *reinterpret_cast<const short8*>(
                    Vs + (ds * 16 + l15) * 128 + (((quad + ks * 4) ^ (l15 & 7)) * 16));
                Oacc[ds] = __builtin_amdgcn_mfma_f32_16x16x32_bf16(vf, pf, Oacc[ds], 0, 0, 0);
            }
        }
    }

    // epilogue: O^T/l -> per-wave LDS [q][d] -> coalesced 16B stores
    const float invl = 1.f / Lacc[0];
#pragma unroll
    for (int ds = 0; ds < 4; ++ds) {
        const int d = ds * 16 + quad * 4;
        *reinterpret_cast<unsigned*>(
            Ps + (d >> 3) * 256 + l15 * 16 + (d & 7) * 2) =
            pack2(Oacc[ds][0] * invl, Oacc[ds][1] * invl);
        *reinterpret_cast<unsigned*>(
            Ps + ((d + 2) >> 3) * 256 + l15 * 16 + ((d + 2) & 7) * 2) =
            pack2(Oacc[ds][2] * invl, Oacc[ds][3] * invl);
    }
#pragma unroll
    for (int it = 0; it < 2; ++it) {
        const int idx = it * 64 + lane;
        const int ch = idx >> 4, q = idx & 15;
        short8 ov = *reinterpret_cast<const short8*>(Ps + ch * 256 + q * 16);
        *reinterpret_cast<short8*>(
            ob + (size_t)(b * SEQ + q0 + w * 16 + q) * D_EMBED + h * 64 + ch * 8) = ov;
    }
}

// ---------------------------------------------------------------------------
extern "C" void kernel_launch(void* const* d_in, const int* in_sizes, int n_in,
                              void* d_out, int out_size, void* d_ws, size_t ws_size,
                              hipStream_t stream)
{
    const float* x     = (const float*)d_in[0];   // [4096, 1024]
    const float* w_qkv = (const float*)d_in[1];   // [1024, 3072]
    const float* b_qkv = (const float*)d_in[2];   // [3072]
    const float* w_o   = (const float*)d_in[3];   // [1024, 1024]
    const float* b_o   = (const float*)d_in[4];   // [1024]
    float* out = (float*)d_out;                   // [4096, 1024] fp32

    bf16* xb     = (bf16*)d_ws;                    // [4096][1024]
    bf16* wqkvT  = xb + (size_t)4096 * 1024;       // [3072][1024]
    bf16* woT    = wqkvT + (size_t)3072 * 1024;    // [1024][1024]
    bf16* qbuf   = woT + (size_t)1024 * 1024;      // [4096][1024] (pre-scaled)
    bf16* kbuf   = qbuf + (size_t)4096 * 1024;     // [4096][1024]
    bf16* vbuf   = kbuf + (size_t)4096 * 1024;     // [4096][1024] row-major
    bf16* vtb    = vbuf + (size_t)4096 * 1024;     // [32 bh][64 d][2048 s]
    bf16* attnb  = vtb + (size_t)4096 * 1024;      // [4096][1024]

    dim3 blk(256);

    // casts
    cast_bf16<<<dim3(4096), blk, 0, stream>>>(x, xb);
    tcast_bf16<<<dim3(48, 16), blk, 0, stream>>>(w_qkv, wqkvT, 1024, 3072);
    tcast_bf16<<<dim3(16, 16), blk, 0, stream>>>(w_o, woT, 1024, 1024);

    // QKV projection (q scaled, k/v row-major)
    gemm_mfma<<<dim3(24, 32), blk, 0, stream>>>(xb, wqkvT, b_qkv, 0,
                                                qbuf, kbuf, vbuf, (float*)nullptr);

    // V transpose for attention B-side staging
    vtrans<<<dim3(32, 32), blk, 0, stream>>>(vbuf, vtb);

    // flash attention
    attn_mfma<<<dim3(32, 32), blk, 0, stream>>>(qbuf, kbuf, vtb, attnb);

    // output projection (fp32 out + bias)
    gemm_mfma<<<dim3(8, 32), blk, 0, stream>>>(attnb, woT, b_o, 1,
                                               (bf16*)nullptr, (bf16*)nullptr,
                                               (bf16*)nullptr, out);
}

// Round 6
// 200.922 us; speedup vs baseline: 26.6831x; 1.0983x over previous
//
#include <hip/hip_runtime.h>
#include <hip/hip_bf16.h>

typedef __hip_bfloat16 bf16;
typedef unsigned short u16;
typedef __attribute__((ext_vector_type(8))) short short8;
typedef __attribute__((ext_vector_type(4))) float floatx4;

#define D_EMBED 1024
#define N_HEADS 16
#define HEAD_DIM 64
#define BATCH 2
#define SEQ 2048
#define ROWS (BATCH * SEQ)          // 4096
#define QKV_COLS (3 * D_EMBED)      // 3072
// exp2-domain scale folded into Q: log2(e)/sqrt(64)
#define QSCALE 0.1803368801f

__device__ __forceinline__ void g2l16(const void* g, void* l) {
    __builtin_amdgcn_global_load_lds(
        (const __attribute__((address_space(1))) unsigned int*)g,
        (__attribute__((address_space(3))) unsigned int*)l,
        16, 0, 0);
}

__device__ __forceinline__ u16 f2b_bits(float f) {
    bf16 h = __float2bfloat16(f);
    u16 u;
    __builtin_memcpy(&u, &h, 2);
    return u;
}

__device__ __forceinline__ unsigned pack2(float a, float b) {   // RNE pack
    return (unsigned)f2b_bits(a) | ((unsigned)f2b_bits(b) << 16);
}

__device__ __forceinline__ float fexp2(float x) {
#if __has_builtin(__builtin_amdgcn_exp2f)
    return __builtin_amdgcn_exp2f(x);
#else
    return exp2f(x);
#endif
}

// pack two fp32 -> two truncated bf16 in one op (low = a, high = b)
__device__ __forceinline__ unsigned permpack(float a, float b) {
#if __has_builtin(__builtin_amdgcn_perm)
    return __builtin_amdgcn_perm(__float_as_uint(b), __float_as_uint(a), 0x07060302u);
#else
    return (__float_as_uint(a) >> 16) | (__float_as_uint(b) & 0xFFFF0000u);
#endif
}

// ---------------------------------------------------------------------------
// Fused prep: cast x -> bf16; transpose+cast w_qkv, w_o. One launch.
// blocks [0,4096): x cast; [4096,4864): w_qkv tcast; [4864,5120): w_o tcast.
// ---------------------------------------------------------------------------
__global__ __launch_bounds__(256)
void prep(const float* __restrict__ x, const float* __restrict__ w_qkv,
          const float* __restrict__ w_o, bf16* __restrict__ xb,
          bf16* __restrict__ wqkvT, bf16* __restrict__ woT)
{
    __shared__ u16 T[64][72];
    const int tid = threadIdx.x;
    const int bid = blockIdx.x;

    if (bid < 4096) {
        const int i = bid * 256 + tid;
        const float4 v = reinterpret_cast<const float4*>(x)[i];
        ushort4 o;
        o.x = f2b_bits(v.x); o.y = f2b_bits(v.y);
        o.z = f2b_bits(v.z); o.w = f2b_bits(v.w);
        reinterpret_cast<ushort4*>(xb)[i] = o;
        return;
    }
    const float* in; u16* out; int R, C, bx, by;
    if (bid < 4864) {
        const int t = bid - 4096;
        in = w_qkv; out = reinterpret_cast<u16*>(wqkvT); R = 1024; C = 3072;
        bx = t % 48; by = t / 48;
    } else {
        const int t = bid - 4864;
        in = w_o; out = reinterpret_cast<u16*>(woT); R = 1024; C = 1024;
        bx = t % 16; by = t / 16;
    }
    const int r0 = by * 64, c0 = bx * 64;
#pragma unroll
    for (int it = 0; it < 4; ++it) {
        const int r = (tid >> 4) + it * 16;
        const int c4 = (tid & 15) * 4;
        const float4 v = *reinterpret_cast<const float4*>(in + (size_t)(r0 + r) * C + c0 + c4);
        T[c4 + 0][r] = f2b_bits(v.x);
        T[c4 + 1][r] = f2b_bits(v.y);
        T[c4 + 2][r] = f2b_bits(v.z);
        T[c4 + 3][r] = f2b_bits(v.w);
    }
    __syncthreads();
#pragma unroll
    for (int it = 0; it < 4; ++it) {
        const int rr = (tid >> 4) + it * 16;
        const int cc4 = (tid & 15) * 4;
        ushort4 o = *reinterpret_cast<const ushort4*>(&T[rr][cc4]);
        *reinterpret_cast<ushort4*>(out + (size_t)(c0 + rr) * R + r0 + cc4) = o;
    }
}

// ---------------------------------------------------------------------------
// bf16 transpose: vb [B*S][1024] (per-head 64 cols) -> vtb [bh*64+d][S].
// ---------------------------------------------------------------------------
__global__ __launch_bounds__(256)
void vtrans(const bf16* __restrict__ vb, bf16* __restrict__ vtb)
{
    __shared__ __align__(16) u16 T[64][72];
    const int tid = threadIdx.x;
    const int s0 = blockIdx.x * 64;
    const int bh = blockIdx.y;
    const int b = bh >> 4, h = bh & 15;
    const u16* src = reinterpret_cast<const u16*>(vb) +
                     (size_t)(b * SEQ + s0) * D_EMBED + h * 64;
    u16* dst = reinterpret_cast<u16*>(vtb) + (size_t)bh * 64 * SEQ + s0;

#pragma unroll
    for (int it = 0; it < 2; ++it) {
        const int idx = it * 256 + tid;
        const int sr = idx >> 3, ch = idx & 7;
        const short8 v = *reinterpret_cast<const short8*>(src + (size_t)sr * D_EMBED + ch * 8);
        *reinterpret_cast<short8*>(&T[sr][ch * 8]) = v;
    }
    __syncthreads();
#pragma unroll
    for (int it = 0; it < 2; ++it) {
        const int idx = it * 256 + tid;
        const int d = idx >> 3, sc = idx & 7;
        u16 tmp[8];
#pragma unroll
        for (int e = 0; e < 8; ++e) tmp[e] = T[sc * 8 + e][d];
        *reinterpret_cast<short8*>(dst + (size_t)d * SEQ + sc * 8) =
            *reinterpret_cast<const short8*>(tmp);
    }
}

// ---------------------------------------------------------------------------
// QKV MFMA GEMM: C[4096,3072] = A @ Bt^T + bias. 128x128 tile, BK=32.
// Epilogue: q (scaled) / k / v row-major bf16 via per-wave LDS repack ->
// 16B coalesced stores.
// ---------------------------------------------------------------------------
__global__ __launch_bounds__(256)
void gemm_qkv(const bf16* __restrict__ A, const bf16* __restrict__ Bt,
              const float* __restrict__ bias,
              bf16* __restrict__ qb, bf16* __restrict__ kb, bf16* __restrict__ vb)
{
    __shared__ __align__(16) char smem[16384];
    char* As = smem;            // [128 m][32 k] bf16, 64B rows
    char* Bs = smem + 8192;     // [128 n][32 k]

    const int tid = threadIdx.x;
    const int lane = tid & 63, w = tid >> 6;
    const int quad = lane >> 4, l15 = lane & 15;
    const int mw = (w >> 1) * 64, nw = (w & 1) * 64;
    const int blockM = blockIdx.y * 128, blockN = blockIdx.x * 128;

    floatx4 acc[4][4];
#pragma unroll
    for (int i = 0; i < 4; ++i)
#pragma unroll
        for (int j = 0; j < 4; ++j) acc[i][j] = (floatx4){0.f, 0.f, 0.f, 0.f};

    for (int k0 = 0; k0 < 1024; k0 += 32) {
        __syncthreads();
#pragma unroll
        for (int it = 0; it < 2; ++it) {
            const int p = it * 256 + tid;
            const int row = p >> 2, ch = p & 3;
            char* dst = As + (it * 256 + (tid & ~63)) * 16;
            g2l16(A + (size_t)(blockM + row) * 1024 + k0 + ch * 8, dst);
            g2l16(Bt + (size_t)(blockN + row) * 1024 + k0 + ch * 8, dst + 8192);
        }
        __syncthreads();

        short8 af[4], bfr[4];
#pragma unroll
        for (int mi = 0; mi < 4; ++mi)
            af[mi] = *reinterpret_cast<const short8*>(
                As + (mw + mi * 16 + l15) * 64 + quad * 16);
#pragma unroll
        for (int ni = 0; ni < 4; ++ni)
            bfr[ni] = *reinterpret_cast<const short8*>(
                Bs + (nw + ni * 16 + l15) * 64 + quad * 16);
#pragma unroll
        for (int mi = 0; mi < 4; ++mi)
#pragma unroll
            for (int ni = 0; ni < 4; ++ni)
                acc[mi][ni] = __builtin_amdgcn_mfma_f32_16x16x32_bf16(
                    af[mi], bfr[ni], acc[mi][ni], 0, 0, 0);
    }

    // epilogue: per-wave LDS repack -> 16B stores
    __syncthreads();                     // everyone done reading As/Bs
    char* W = smem + w * 2304;           // [16 rows][stride 144B]
    const bool isq = (blockN < 1024);
    const bool isv = (blockN >= 2048);
    bf16* dstbuf = isq ? qb : (isv ? vb : kb);
    const int coloff = blockN - (isq ? 0 : (isv ? 2048 : 1024));

#pragma unroll
    for (int mi = 0; mi < 4; ++mi) {
#pragma unroll
        for (int ni = 0; ni < 4; ++ni) {
            const float bv = bias[blockN + nw + ni * 16 + l15];
#pragma unroll
            for (int r = 0; r < 4; ++r) {
                float val = acc[mi][ni][r] + bv;
                if (isq) val *= QSCALE;
                *reinterpret_cast<u16*>(
                    W + (quad * 4 + r) * 144 + (ni * 16 + l15) * 2) = f2b_bits(val);
            }
        }
#pragma unroll
        for (int half = 0; half < 2; ++half) {
            const int idx = half * 64 + lane;
            const int rowL = idx >> 3, ch = idx & 7;
            short8 v = *reinterpret_cast<const short8*>(W + rowL * 144 + ch * 16);
            const int grow = blockM + mw + mi * 16 + rowL;
            const int gcol = coloff + nw + ch * 8;
            *reinterpret_cast<short8*>(
                reinterpret_cast<u16*>(dstbuf) + (size_t)grow * 1024 + gcol) = v;
        }
    }
}

// ---------------------------------------------------------------------------
// Out-proj MFMA GEMM: out[4096,1024] = A @ Bt^T + bias (fp32 out).
// 128m x 64n tile -> 512 blocks (2/CU). Waves 2x2: 64m x 32n each.
// ---------------------------------------------------------------------------
__global__ __launch_bounds__(256)
void gemm_out(const bf16* __restrict__ A, const bf16* __restrict__ Bt,
              const float* __restrict__ bias, float* __restrict__ outf)
{
    __shared__ __align__(16) char smem[12288];
    char* As = smem;            // [128 m][32 k]
    char* Bs = smem + 8192;     // [64 n][32 k]

    const int tid = threadIdx.x;
    const int lane = tid & 63, w = tid >> 6;
    const int quad = lane >> 4, l15 = lane & 15;
    const int mw = (w >> 1) * 64, nw = (w & 1) * 32;
    const int blockM = blockIdx.y * 128, blockN = blockIdx.x * 64;

    floatx4 acc[4][2];
#pragma unroll
    for (int i = 0; i < 4; ++i)
#pragma unroll
        for (int j = 0; j < 2; ++j) acc[i][j] = (floatx4){0.f, 0.f, 0.f, 0.f};

    for (int k0 = 0; k0 < 1024; k0 += 32) {
        __syncthreads();
#pragma unroll
        for (int it = 0; it < 2; ++it) {
            const int p = it * 256 + tid;
            const int row = p >> 2, ch = p & 3;
            g2l16(A + (size_t)(blockM + row) * 1024 + k0 + ch * 8,
                  As + (it * 256 + (tid & ~63)) * 16);
        }
        {
            const int row = tid >> 2, ch = tid & 3;
            g2l16(Bt + (size_t)(blockN + row) * 1024 + k0 + ch * 8,
                  Bs + (tid & ~63) * 16);
        }
        __syncthreads();

        short8 af[4], bfr[2];
#pragma unroll
        for (int mi = 0; mi < 4; ++mi)
            af[mi] = *reinterpret_cast<const short8*>(
                As + (mw + mi * 16 + l15) * 64 + quad * 16);
#pragma unroll
        for (int ni = 0; ni < 2; ++ni)
            bfr[ni] = *reinterpret_cast<const short8*>(
                Bs + (nw + ni * 16 + l15) * 64 + quad * 16);
#pragma unroll
        for (int mi = 0; mi < 4; ++mi)
#pragma unroll
            for (int ni = 0; ni < 2; ++ni)
                acc[mi][ni] = __builtin_amdgcn_mfma_f32_16x16x32_bf16(
                    af[mi], bfr[ni], acc[mi][ni], 0, 0, 0);
    }

#pragma unroll
    for (int mi = 0; mi < 4; ++mi)
#pragma unroll
        for (int r = 0; r < 4; ++r) {
            const int row = blockM + mw + mi * 16 + quad * 4 + r;
#pragma unroll
            for (int ni = 0; ni < 2; ++ni) {
                const int col = blockN + nw + ni * 16 + l15;
                outf[(size_t)row * 1024 + col] = acc[mi][ni][r] + bias[col];
            }
        }
}

// ---------------------------------------------------------------------------
// MFMA flash attention (causal), max-free exp2-domain softmax, Q-tile 128.
// Block = (q-tile 128, bh); 4 waves, wave w owns q cols [w*32, w*32+32).
//   S^T = K·Q^T (Q pre-scaled)  C-layout: k_s=quad*4+r, q=l15
//   P = exp2(S^T); l = ones-MFMA column sum; O^T += V^T·P.
// K/V fragments reused across both q-fragments -> 20 LDS reads / 36 MFMAs.
// ---------------------------------------------------------------------------
__global__ __launch_bounds__(256, 3)
void attn_mfma(const bf16* __restrict__ qb, const bf16* __restrict__ kb,
               const bf16* __restrict__ vtb, bf16* __restrict__ ob)
{
    __shared__ __align__(16) char smem[49152];
    char* Qs = smem;              // [128 q][64 d] swizzled, 16 KB
    char* Ks = smem + 16384;      // [64 s][64 d] swizzled, 8 KB
    char* Vs = smem + 24576;      // [64 d][64 s] swizzled, 8 KB
    const int tid = threadIdx.x;
    const int lane = tid & 63, w = tid >> 6;
    const int quad = lane >> 4, l15 = lane & 15;
    char* Ps = smem + 32768 + w * 4096;   // per-wave [8 kchunk][32 q][16B]

    const int qt = gridDim.x - 1 - blockIdx.x;   // heavy blocks first
    const int bh = blockIdx.y;
    const int b = bh >> 4, h = bh & 15;
    const int q0 = qt * 128;
    const int qw = q0 + w * 32;

    // stage Q tile (128 rows)
#pragma unroll
    for (int it = 0; it < 4; ++it) {
        const int p = it * 256 + tid;
        const int row = p >> 3;
        const int lch = (p & 7) ^ (row & 7);
        g2l16(qb + (size_t)(b * SEQ + q0 + row) * D_EMBED + h * 64 + lch * 8,
              Qs + (it * 256 + (tid & ~63)) * 16);
    }

    floatx4 Oacc[2][4], Lacc[2];
#pragma unroll
    for (int j = 0; j < 2; ++j) {
        Lacc[j] = (floatx4){0.f, 0.f, 0.f, 0.f};
#pragma unroll
        for (int i = 0; i < 4; ++i) Oacc[j][i] = (floatx4){0.f, 0.f, 0.f, 0.f};
    }
    const short8 ones = {0x3F80, 0x3F80, 0x3F80, 0x3F80,
                         0x3F80, 0x3F80, 0x3F80, 0x3F80};   // bf16 1.0 x8
    short8 qf[2][2];

    const int kts = 2 * qt + 2;
    for (int kt = 0; kt < kts; ++kt) {
        const int k0 = kt * 64;
        __syncthreads();
#pragma unroll
        for (int it = 0; it < 2; ++it) {
            const int p = it * 256 + tid;
            const int row = p >> 3;
            const int lch = (p & 7) ^ (row & 7);
            char* dst = Ks + (it * 256 + (tid & ~63)) * 16;
            g2l16(kb + (size_t)(b * SEQ + k0 + row) * D_EMBED + h * 64 + lch * 8, dst);
            g2l16(vtb + (size_t)(bh * 64 + row) * SEQ + k0 + lch * 8, dst + 8192);
        }
        __syncthreads();

        if (kt == 0) {
#pragma unroll
            for (int j = 0; j < 2; ++j) {
                const int row = w * 32 + j * 16 + l15;
                qf[j][0] = *reinterpret_cast<const short8*>(
                    Qs + row * 128 + ((quad ^ (l15 & 7)) * 16));
                qf[j][1] = *reinterpret_cast<const short8*>(
                    Qs + row * 128 + (((quad + 4) ^ (l15 & 7)) * 16));
            }
        }

        if (k0 <= qw + 31) {        // wave has at least one unmasked element
            // S^T = K · Q^T
            floatx4 S[2][4];
#pragma unroll
            for (int ms = 0; ms < 4; ++ms) {
                const short8 kf0 = *reinterpret_cast<const short8*>(
                    Ks + (ms * 16 + l15) * 128 + ((quad ^ (l15 & 7)) * 16));
                const short8 kf1 = *reinterpret_cast<const short8*>(
                    Ks + (ms * 16 + l15) * 128 + (((quad + 4) ^ (l15 & 7)) * 16));
#pragma unroll
                for (int j = 0; j < 2; ++j) {
                    floatx4 t = (floatx4){0.f, 0.f, 0.f, 0.f};
                    t = __builtin_amdgcn_mfma_f32_16x16x32_bf16(kf0, qf[j][0], t, 0, 0, 0);
                    S[j][ms] = __builtin_amdgcn_mfma_f32_16x16x32_bf16(kf1, qf[j][1], t, 0, 0, 0);
                }
            }

            // P = exp2(S) with causal mask on edge tiles; write to per-wave LDS
            const bool edge = (k0 + 63 > qw);
#pragma unroll
            for (int j = 0; j < 2; ++j) {
                const int qrow = qw + j * 16 + l15;
#pragma unroll
                for (int ms = 0; ms < 4; ++ms) {
                    float p[4];
#pragma unroll
                    for (int r = 0; r < 4; ++r) {
                        float s = S[j][ms][r];
                        if (edge && (k0 + ms * 16 + quad * 4 + r) > qrow) s = -1e30f;
                        p[r] = fexp2(s);
                    }
                    const int k = ms * 16 + quad * 4;
                    uint2 pw;
                    pw.x = permpack(p[0], p[1]);
                    pw.y = permpack(p[2], p[3]);
                    *reinterpret_cast<uint2*>(
                        Ps + (k >> 3) * 512 + (j * 16 + l15) * 16 + (k & 7) * 2) = pw;
                }
            }

            // l += 1^T·P ;  O^T += V^T·P  (V fragments shared across j)
#pragma unroll
            for (int ks = 0; ks < 2; ++ks) {
                short8 pf[2];
#pragma unroll
                for (int j = 0; j < 2; ++j)
                    pf[j] = *reinterpret_cast<const short8*>(
                        Ps + (ks * 4 + quad) * 512 + (j * 16 + l15) * 16);
                Lacc[0] = __builtin_amdgcn_mfma_f32_16x16x32_bf16(ones, pf[0], Lacc[0], 0, 0, 0);
                Lacc[1] = __builtin_amdgcn_mfma_f32_16x16x32_bf16(ones, pf[1], Lacc[1], 0, 0, 0);
#pragma unroll
                for (int ds = 0; ds < 4; ++ds) {
                    const short8 vf = *reinterpret_cast<const short8*>(
                        Vs + (ds * 16 + l15) * 128 + (((ks * 4 + quad) ^ (l15 & 7)) * 16));
                    Oacc[0][ds] = __builtin_amdgcn_mfma_f32_16x16x32_bf16(vf, pf[0], Oacc[0][ds], 0, 0, 0);
                    Oacc[1][ds] = __builtin_amdgcn_mfma_f32_16x16x32_bf16(vf, pf[1], Oacc[1][ds], 0, 0, 0);
                }
            }
        }
    }

    // epilogue: O^T/l -> per-wave LDS [q][d] -> coalesced 16B stores
#pragma unroll
    for (int j = 0; j < 2; ++j) {
        const float invl = 1.f / Lacc[j][0];
#pragma unroll
        for (int ds = 0; ds < 4; ++ds) {
            const int d = ds * 16 + quad * 4;
            uint2 ow;
            ow.x = pack2(Oacc[j][ds][0] * invl, Oacc[j][ds][1] * invl);
            ow.y = pack2(Oacc[j][ds][2] * invl, Oacc[j][ds][3] * invl);
            *reinterpret_cast<uint2*>(
                Ps + (d >> 3) * 512 + (j * 16 + l15) * 16 + (d & 7) * 2) = ow;
        }
    }
#pragma unroll
    for (int it = 0; it < 4; ++it) {
        const int idx = it * 64 + lane;
        const int q = idx >> 3, ch = idx & 7;
        short8 ov = *reinterpret_cast<const short8*>(Ps + ch * 512 + q * 16);
        *reinterpret_cast<short8*>(
            ob + (size_t)(b * SEQ + q0 + w * 32 + q) * D_EMBED + h * 64 + ch * 8) = ov;
    }
}

// ---------------------------------------------------------------------------
extern "C" void kernel_launch(void* const* d_in, const int* in_sizes, int n_in,
                              void* d_out, int out_size, void* d_ws, size_t ws_size,
                              hipStream_t stream)
{
    const float* x     = (const float*)d_in[0];   // [4096, 1024]
    const float* w_qkv = (const float*)d_in[1];   // [1024, 3072]
    const float* b_qkv = (const float*)d_in[2];   // [3072]
    const float* w_o   = (const float*)d_in[3];   // [1024, 1024]
    const float* b_o   = (const float*)d_in[4];   // [1024]
    float* out = (float*)d_out;                   // [4096, 1024] fp32

    bf16* xb     = (bf16*)d_ws;                    // [4096][1024]
    bf16* wqkvT  = xb + (size_t)4096 * 1024;       // [3072][1024]
    bf16* woT    = wqkvT + (size_t)3072 * 1024;    // [1024][1024]
    bf16* qbuf   = woT + (size_t)1024 * 1024;      // [4096][1024] (pre-scaled)
    bf16* kbuf   = qbuf + (size_t)4096 * 1024;     // [4096][1024]
    bf16* vbuf   = kbuf + (size_t)4096 * 1024;     // [4096][1024] row-major
    bf16* vtb    = vbuf + (size_t)4096 * 1024;     // [32 bh][64 d][2048 s]
    bf16* attnb  = vtb + (size_t)4096 * 1024;      // [4096][1024]

    dim3 blk(256);

    // fused casts
    prep<<<dim3(5120), blk, 0, stream>>>(x, w_qkv, w_o, xb, wqkvT, woT);

    // QKV projection (q scaled, k/v row-major; coalesced epilogue)
    gemm_qkv<<<dim3(24, 32), blk, 0, stream>>>(xb, wqkvT, b_qkv, qbuf, kbuf, vbuf);

    // V transpose for attention A-operand staging
    vtrans<<<dim3(32, 32), blk, 0, stream>>>(vbuf, vtb);

    // flash attention, Q-tile 128
    attn_mfma<<<dim3(16, 32), blk, 0, stream>>>(qbuf, kbuf, vtb, attnb);

    // output projection (fp32 out + bias), 512 blocks
    gemm_out<<<dim3(16, 32), blk, 0, stream>>>(attnb, woT, b_o, out);
}

// Round 7
// 184.634 us; speedup vs baseline: 29.0372x; 1.0882x over previous
//
#include <hip/hip_runtime.h>
#include <hip/hip_bf16.h>

typedef __hip_bfloat16 bf16;
typedef unsigned short u16;
typedef __attribute__((ext_vector_type(8))) short short8;
typedef __attribute__((ext_vector_type(4))) float floatx4;

#define D_EMBED 1024
#define N_HEADS 16
#define HEAD_DIM 64
#define BATCH 2
#define SEQ 2048
#define ROWS (BATCH * SEQ)          // 4096
#define QKV_COLS (3 * D_EMBED)      // 3072
// exp2-domain scale folded into Q: log2(e)/sqrt(64)
#define QSCALE 0.1803368801f

__device__ __forceinline__ void g2l16(const void* g, void* l) {
    __builtin_amdgcn_global_load_lds(
        (const __attribute__((address_space(1))) unsigned int*)g,
        (__attribute__((address_space(3))) unsigned int*)l,
        16, 0, 0);
}

__device__ __forceinline__ u16 f2b_bits(float f) {
    bf16 h = __float2bfloat16(f);
    u16 u;
    __builtin_memcpy(&u, &h, 2);
    return u;
}

__device__ __forceinline__ unsigned pack2(float a, float b) {   // RNE pack
    return (unsigned)f2b_bits(a) | ((unsigned)f2b_bits(b) << 16);
}

__device__ __forceinline__ float fexp2(float x) {
#if __has_builtin(__builtin_amdgcn_exp2f)
    return __builtin_amdgcn_exp2f(x);
#else
    return exp2f(x);
#endif
}

// pack two fp32 -> two truncated bf16 in one op (low = a, high = b)
__device__ __forceinline__ unsigned permpack(float a, float b) {
#if __has_builtin(__builtin_amdgcn_perm)
    return __builtin_amdgcn_perm(__float_as_uint(b), __float_as_uint(a), 0x07060302u);
#else
    return (__float_as_uint(a) >> 16) | (__float_as_uint(b) & 0xFFFF0000u);
#endif
}

// ---------------------------------------------------------------------------
// Fused prep: cast x -> bf16; transpose+cast w_qkv, w_o.
// ---------------------------------------------------------------------------
__global__ __launch_bounds__(256)
void prep(const float* __restrict__ x, const float* __restrict__ w_qkv,
          const float* __restrict__ w_o, bf16* __restrict__ xb,
          bf16* __restrict__ wqkvT, bf16* __restrict__ woT)
{
    __shared__ u16 T[64][72];
    const int tid = threadIdx.x;
    const int bid = blockIdx.x;

    if (bid < 4096) {
        const int i = bid * 256 + tid;
        const float4 v = reinterpret_cast<const float4*>(x)[i];
        ushort4 o;
        o.x = f2b_bits(v.x); o.y = f2b_bits(v.y);
        o.z = f2b_bits(v.z); o.w = f2b_bits(v.w);
        reinterpret_cast<ushort4*>(xb)[i] = o;
        return;
    }
    const float* in; u16* out; int R, C, bx, by;
    if (bid < 4864) {
        const int t = bid - 4096;
        in = w_qkv; out = reinterpret_cast<u16*>(wqkvT); R = 1024; C = 3072;
        bx = t % 48; by = t / 48;
    } else {
        const int t = bid - 4864;
        in = w_o; out = reinterpret_cast<u16*>(woT); R = 1024; C = 1024;
        bx = t % 16; by = t / 16;
    }
    const int r0 = by * 64, c0 = bx * 64;
#pragma unroll
    for (int it = 0; it < 4; ++it) {
        const int r = (tid >> 4) + it * 16;
        const int c4 = (tid & 15) * 4;
        const float4 v = *reinterpret_cast<const float4*>(in + (size_t)(r0 + r) * C + c0 + c4);
        T[c4 + 0][r] = f2b_bits(v.x);
        T[c4 + 1][r] = f2b_bits(v.y);
        T[c4 + 2][r] = f2b_bits(v.z);
        T[c4 + 3][r] = f2b_bits(v.w);
    }
    __syncthreads();
#pragma unroll
    for (int it = 0; it < 4; ++it) {
        const int rr = (tid >> 4) + it * 16;
        const int cc4 = (tid & 15) * 4;
        ushort4 o = *reinterpret_cast<const ushort4*>(&T[rr][cc4]);
        *reinterpret_cast<ushort4*>(out + (size_t)(c0 + rr) * R + r0 + cc4) = o;
    }
}

// ---------------------------------------------------------------------------
// bf16 transpose: vb [B*S][1024] (per-head 64 cols) -> vtb [bh*64+d][S].
// ---------------------------------------------------------------------------
__global__ __launch_bounds__(256)
void vtrans(const bf16* __restrict__ vb, bf16* __restrict__ vtb)
{
    __shared__ __align__(16) u16 T[64][72];
    const int tid = threadIdx.x;
    const int s0 = blockIdx.x * 64;
    const int bh = blockIdx.y;
    const int b = bh >> 4, h = bh & 15;
    const u16* src = reinterpret_cast<const u16*>(vb) +
                     (size_t)(b * SEQ + s0) * D_EMBED + h * 64;
    u16* dst = reinterpret_cast<u16*>(vtb) + (size_t)bh * 64 * SEQ + s0;

#pragma unroll
    for (int it = 0; it < 2; ++it) {
        const int idx = it * 256 + tid;
        const int sr = idx >> 3, ch = idx & 7;
        const short8 v = *reinterpret_cast<const short8*>(src + (size_t)sr * D_EMBED + ch * 8);
        *reinterpret_cast<short8*>(&T[sr][ch * 8]) = v;
    }
    __syncthreads();
#pragma unroll
    for (int it = 0; it < 2; ++it) {
        const int idx = it * 256 + tid;
        const int d = idx >> 3, sc = idx & 7;
        u16 tmp[8];
#pragma unroll
        for (int e = 0; e < 8; ++e) tmp[e] = T[sc * 8 + e][d];
        *reinterpret_cast<short8*>(dst + (size_t)d * SEQ + sc * 8) =
            *reinterpret_cast<const short8*>(tmp);
    }
}

// ---------------------------------------------------------------------------
// QKV MFMA GEMM: C[4096,3072] = A @ Bt^T + bias. 128x128 tile, BK=32.
// Epilogue: q (scaled) / k / v row-major bf16 via per-wave LDS repack.
// ---------------------------------------------------------------------------
__global__ __launch_bounds__(256)
void gemm_qkv(const bf16* __restrict__ A, const bf16* __restrict__ Bt,
              const float* __restrict__ bias,
              bf16* __restrict__ qb, bf16* __restrict__ kb, bf16* __restrict__ vb)
{
    __shared__ __align__(16) char smem[16384];
    char* As = smem;            // [128 m][32 k] bf16, 64B rows
    char* Bs = smem + 8192;     // [128 n][32 k]

    const int tid = threadIdx.x;
    const int lane = tid & 63, w = tid >> 6;
    const int quad = lane >> 4, l15 = lane & 15;
    const int mw = (w >> 1) * 64, nw = (w & 1) * 64;
    const int blockM = blockIdx.y * 128, blockN = blockIdx.x * 128;

    floatx4 acc[4][4];
#pragma unroll
    for (int i = 0; i < 4; ++i)
#pragma unroll
        for (int j = 0; j < 4; ++j) acc[i][j] = (floatx4){0.f, 0.f, 0.f, 0.f};

    for (int k0 = 0; k0 < 1024; k0 += 32) {
        __syncthreads();
#pragma unroll
        for (int it = 0; it < 2; ++it) {
            const int p = it * 256 + tid;
            const int row = p >> 2, ch = p & 3;
            char* dst = As + (it * 256 + (tid & ~63)) * 16;
            g2l16(A + (size_t)(blockM + row) * 1024 + k0 + ch * 8, dst);
            g2l16(Bt + (size_t)(blockN + row) * 1024 + k0 + ch * 8, dst + 8192);
        }
        __syncthreads();

        short8 af[4], bfr[4];
#pragma unroll
        for (int mi = 0; mi < 4; ++mi)
            af[mi] = *reinterpret_cast<const short8*>(
                As + (mw + mi * 16 + l15) * 64 + quad * 16);
#pragma unroll
        for (int ni = 0; ni < 4; ++ni)
            bfr[ni] = *reinterpret_cast<const short8*>(
                Bs + (nw + ni * 16 + l15) * 64 + quad * 16);
#pragma unroll
        for (int mi = 0; mi < 4; ++mi)
#pragma unroll
            for (int ni = 0; ni < 4; ++ni)
                acc[mi][ni] = __builtin_amdgcn_mfma_f32_16x16x32_bf16(
                    af[mi], bfr[ni], acc[mi][ni], 0, 0, 0);
    }

    // epilogue: per-wave LDS repack -> 16B stores
    __syncthreads();
    char* W = smem + w * 2304;           // [16 rows][stride 144B]
    const bool isq = (blockN < 1024);
    const bool isv = (blockN >= 2048);
    bf16* dstbuf = isq ? qb : (isv ? vb : kb);
    const int coloff = blockN - (isq ? 0 : (isv ? 2048 : 1024));

    float bvn[4];                        // hoisted bias (4 loads, not 16)
#pragma unroll
    for (int ni = 0; ni < 4; ++ni) bvn[ni] = bias[blockN + nw + ni * 16 + l15];

#pragma unroll
    for (int mi = 0; mi < 4; ++mi) {
#pragma unroll
        for (int ni = 0; ni < 4; ++ni) {
#pragma unroll
            for (int r = 0; r < 4; ++r) {
                float val = acc[mi][ni][r] + bvn[ni];
                if (isq) val *= QSCALE;
                *reinterpret_cast<u16*>(
                    W + (quad * 4 + r) * 144 + (ni * 16 + l15) * 2) = f2b_bits(val);
            }
        }
#pragma unroll
        for (int half = 0; half < 2; ++half) {
            const int idx = half * 64 + lane;
            const int rowL = idx >> 3, ch = idx & 7;
            short8 v = *reinterpret_cast<const short8*>(W + rowL * 144 + ch * 16);
            const int grow = blockM + mw + mi * 16 + rowL;
            const int gcol = coloff + nw + ch * 8;
            *reinterpret_cast<short8*>(
                reinterpret_cast<u16*>(dstbuf) + (size_t)grow * 1024 + gcol) = v;
        }
    }
}

// ---------------------------------------------------------------------------
// Out-proj MFMA GEMM: out[4096,1024] = A @ Bt^T + bias (fp32 out).
// 128m x 64n tile -> 512 blocks (2/CU).
// ---------------------------------------------------------------------------
__global__ __launch_bounds__(256)
void gemm_out(const bf16* __restrict__ A, const bf16* __restrict__ Bt,
              const float* __restrict__ bias, float* __restrict__ outf)
{
    __shared__ __align__(16) char smem[12288];
    char* As = smem;            // [128 m][32 k]
    char* Bs = smem + 8192;     // [64 n][32 k]

    const int tid = threadIdx.x;
    const int lane = tid & 63, w = tid >> 6;
    const int quad = lane >> 4, l15 = lane & 15;
    const int mw = (w >> 1) * 64, nw = (w & 1) * 32;
    const int blockM = blockIdx.y * 128, blockN = blockIdx.x * 64;

    floatx4 acc[4][2];
#pragma unroll
    for (int i = 0; i < 4; ++i)
#pragma unroll
        for (int j = 0; j < 2; ++j) acc[i][j] = (floatx4){0.f, 0.f, 0.f, 0.f};

    for (int k0 = 0; k0 < 1024; k0 += 32) {
        __syncthreads();
#pragma unroll
        for (int it = 0; it < 2; ++it) {
            const int p = it * 256 + tid;
            const int row = p >> 2, ch = p & 3;
            g2l16(A + (size_t)(blockM + row) * 1024 + k0 + ch * 8,
                  As + (it * 256 + (tid & ~63)) * 16);
        }
        {
            const int row = tid >> 2, ch = tid & 3;
            g2l16(Bt + (size_t)(blockN + row) * 1024 + k0 + ch * 8,
                  Bs + (tid & ~63) * 16);
        }
        __syncthreads();

        short8 af[4], bfr[2];
#pragma unroll
        for (int mi = 0; mi < 4; ++mi)
            af[mi] = *reinterpret_cast<const short8*>(
                As + (mw + mi * 16 + l15) * 64 + quad * 16);
#pragma unroll
        for (int ni = 0; ni < 2; ++ni)
            bfr[ni] = *reinterpret_cast<const short8*>(
                Bs + (nw + ni * 16 + l15) * 64 + quad * 16);
#pragma unroll
        for (int mi = 0; mi < 4; ++mi)
#pragma unroll
            for (int ni = 0; ni < 2; ++ni)
                acc[mi][ni] = __builtin_amdgcn_mfma_f32_16x16x32_bf16(
                    af[mi], bfr[ni], acc[mi][ni], 0, 0, 0);
    }

    float bvn[2];
#pragma unroll
    for (int ni = 0; ni < 2; ++ni) bvn[ni] = bias[blockN + nw + ni * 16 + l15];

#pragma unroll
    for (int mi = 0; mi < 4; ++mi)
#pragma unroll
        for (int r = 0; r < 4; ++r) {
            const int row = blockM + mw + mi * 16 + quad * 4 + r;
#pragma unroll
            for (int ni = 0; ni < 2; ++ni) {
                const int col = blockN + nw + ni * 16 + l15;
                outf[(size_t)row * 1024 + col] = acc[mi][ni][r] + bvn[ni];
            }
        }
}

// ---------------------------------------------------------------------------
// MFMA flash attention (causal), max-free exp2-domain softmax.
// Causal PAIRING for balance: block (pair i, bh) processes q-tile 31-i then
// q-tile i (64 q each). Every block = 33 k-tile iterations + 2 setups.
// Double-buffered K/V staging: stage kt+1 while computing kt; ONE barrier
// per iteration (its vmcnt(0) drain finds the prefetch already landed).
//   S^T = K·Q^T (Q pre-scaled)  C-layout: k_s=quad*4+r, q=l15
//   P = exp2(S^T); l = ones-MFMA column sum; O^T += V^T·P.
// LDS: Q 8K | KV dbuf 2x16K | P per-wave 4x2K = 48 KB.
// ---------------------------------------------------------------------------
__global__ __launch_bounds__(256)
void attn_mfma(const bf16* __restrict__ qb, const bf16* __restrict__ kb,
               const bf16* __restrict__ vtb, bf16* __restrict__ ob)
{
    __shared__ __align__(16) char smem[49152];
    char* Qs = smem;                      // [64 q][64 d] swizzled, 8 KB
    char* KV0 = smem + 8192;              // Ks 8K + Vs 8K
    char* KV1 = smem + 24576;
    const int tid = threadIdx.x;
    const int lane = tid & 63, w = tid >> 6;
    const int quad = lane >> 4, l15 = lane & 15;
    char* Ps = smem + 40960 + w * 2048;   // per-wave [8 kchunk][16 q][16B]

    const int pi = blockIdx.x;            // pair index 0..15
    const int bh = blockIdx.y;
    const int b = bh >> 4, h = bh & 15;

    const size_t kvrow = (size_t)b * SEQ;
    const size_t vbase = (size_t)bh * 64 * SEQ;

    const short8 ones = {0x3F80, 0x3F80, 0x3F80, 0x3F80,
                         0x3F80, 0x3F80, 0x3F80, 0x3F80};   // bf16 1.0 x8

#pragma unroll 1
    for (int phase = 0; phase < 2; ++phase) {
        const int qt = (phase == 0) ? (31 - pi) : pi;
        const int q0 = qt * 64;
        const int qrow = q0 + w * 16 + l15;

        // stage Q tile + K/V tile kt=0 into KV0
#pragma unroll
        for (int it = 0; it < 2; ++it) {
            const int p = it * 256 + tid;
            const int row = p >> 3;
            const int lch = (p & 7) ^ (row & 7);
            g2l16(qb + (kvrow + q0 + row) * D_EMBED + h * 64 + lch * 8,
                  Qs + (it * 256 + (tid & ~63)) * 16);
            char* dst = KV0 + (it * 256 + (tid & ~63)) * 16;
            g2l16(kb + (kvrow + row) * D_EMBED + h * 64 + lch * 8, dst);
            g2l16(vtb + vbase + (size_t)row * SEQ + lch * 8, dst + 8192);
        }
        __syncthreads();

        const short8 qf0 = *reinterpret_cast<const short8*>(
            Qs + (w * 16 + l15) * 128 + ((quad ^ (l15 & 7)) * 16));
        const short8 qf1 = *reinterpret_cast<const short8*>(
            Qs + (w * 16 + l15) * 128 + (((quad + 4) ^ (l15 & 7)) * 16));

        floatx4 Oacc[4], Lacc;
#pragma unroll
        for (int i = 0; i < 4; ++i) Oacc[i] = (floatx4){0.f, 0.f, 0.f, 0.f};
        Lacc = (floatx4){0.f, 0.f, 0.f, 0.f};

#pragma unroll 1
        for (int kt = 0; kt <= qt; ++kt) {
            char* cur = (kt & 1) ? KV1 : KV0;
            // prefetch next K/V tile into the spare buffer
            if (kt < qt) {
                char* nxt = (kt & 1) ? KV0 : KV1;
                const int nk0 = (kt + 1) * 64;
#pragma unroll
                for (int it = 0; it < 2; ++it) {
                    const int p = it * 256 + tid;
                    const int row = p >> 3;
                    const int lch = (p & 7) ^ (row & 7);
                    char* dst = nxt + (it * 256 + (tid & ~63)) * 16;
                    g2l16(kb + (kvrow + nk0 + row) * D_EMBED + h * 64 + lch * 8, dst);
                    g2l16(vtb + vbase + (size_t)row * SEQ + nk0 + lch * 8, dst + 8192);
                }
            }
            const int k0 = kt * 64;
            char* Ks = cur;
            char* Vs = cur + 8192;

            // S^T = K · Q^T
            floatx4 Sacc[4];
#pragma unroll
            for (int ms = 0; ms < 4; ++ms) {
                Sacc[ms] = (floatx4){0.f, 0.f, 0.f, 0.f};
                const short8 kf0 = *reinterpret_cast<const short8*>(
                    Ks + (ms * 16 + l15) * 128 + ((quad ^ (l15 & 7)) * 16));
                Sacc[ms] = __builtin_amdgcn_mfma_f32_16x16x32_bf16(kf0, qf0, Sacc[ms], 0, 0, 0);
                const short8 kf1 = *reinterpret_cast<const short8*>(
                    Ks + (ms * 16 + l15) * 128 + (((quad + 4) ^ (l15 & 7)) * 16));
                Sacc[ms] = __builtin_amdgcn_mfma_f32_16x16x32_bf16(kf1, qf1, Sacc[ms], 0, 0, 0);
            }

            // P = exp2(S^T) (+ causal mask on diagonal tile), write per-wave LDS
            const bool diag = (kt == qt);
#pragma unroll
            for (int ms = 0; ms < 4; ++ms) {
                float p[4];
#pragma unroll
                for (int r = 0; r < 4; ++r) {
                    float s = Sacc[ms][r];
                    if (diag && (k0 + ms * 16 + quad * 4 + r) > qrow) s = -1e30f;
                    p[r] = fexp2(s);
                }
                const int k = ms * 16 + quad * 4;
                uint2 pw;
                pw.x = permpack(p[0], p[1]);
                pw.y = permpack(p[2], p[3]);
                *reinterpret_cast<uint2*>(Ps + (k >> 3) * 256 + l15 * 16 + (k & 7) * 2) = pw;
            }

            // l += 1^T·P ;  O^T += V^T·P
#pragma unroll
            for (int ks = 0; ks < 2; ++ks) {
                const short8 pf = *reinterpret_cast<const short8*>(
                    Ps + (ks * 4 + quad) * 256 + l15 * 16);
                Lacc = __builtin_amdgcn_mfma_f32_16x16x32_bf16(ones, pf, Lacc, 0, 0, 0);
#pragma unroll
                for (int ds = 0; ds < 4; ++ds) {
                    const short8 vf = *reinterpret_cast<const short8*>(
                        Vs + (ds * 16 + l15) * 128 + (((quad + ks * 4) ^ (l15 & 7)) * 16));
                    Oacc[ds] = __builtin_amdgcn_mfma_f32_16x16x32_bf16(vf, pf, Oacc[ds], 0, 0, 0);
                }
            }
            __syncthreads();   // publish prefetched tile; frees cur for restage
        }

        // epilogue: O^T/l -> per-wave LDS [q][d] -> coalesced 16B stores
        const float invl = 1.f / Lacc[0];
#pragma unroll
        for (int ds = 0; ds < 4; ++ds) {
            const int d = ds * 16 + quad * 4;
            uint2 ow;
            ow.x = pack2(Oacc[ds][0] * invl, Oacc[ds][1] * invl);
            ow.y = pack2(Oacc[ds][2] * invl, Oacc[ds][3] * invl);
            *reinterpret_cast<uint2*>(
                Ps + (d >> 3) * 256 + l15 * 16 + (d & 7) * 2) = ow;
        }
#pragma unroll
        for (int it = 0; it < 2; ++it) {
            const int idx = it * 64 + lane;
            const int ch = idx >> 4, q = idx & 15;
            short8 ov = *reinterpret_cast<const short8*>(Ps + ch * 256 + q * 16);
            *reinterpret_cast<short8*>(
                ob + (kvrow + q0 + w * 16 + q) * D_EMBED + h * 64 + ch * 8) = ov;
        }
    }
}

// ---------------------------------------------------------------------------
extern "C" void kernel_launch(void* const* d_in, const int* in_sizes, int n_in,
                              void* d_out, int out_size, void* d_ws, size_t ws_size,
                              hipStream_t stream)
{
    const float* x     = (const float*)d_in[0];   // [4096, 1024]
    const float* w_qkv = (const float*)d_in[1];   // [1024, 3072]
    const float* b_qkv = (const float*)d_in[2];   // [3072]
    const float* w_o   = (const float*)d_in[3];   // [1024, 1024]
    const float* b_o   = (const float*)d_in[4];   // [1024]
    float* out = (float*)d_out;                   // [4096, 1024] fp32

    bf16* xb     = (bf16*)d_ws;                    // [4096][1024]
    bf16* wqkvT  = xb + (size_t)4096 * 1024;       // [3072][1024]
    bf16* woT    = wqkvT + (size_t)3072 * 1024;    // [1024][1024]
    bf16* qbuf   = woT + (size_t)1024 * 1024;      // [4096][1024] (pre-scaled)
    bf16* kbuf   = qbuf + (size_t)4096 * 1024;     // [4096][1024]
    bf16* vbuf   = kbuf + (size_t)4096 * 1024;     // [4096][1024] row-major
    bf16* vtb    = vbuf + (size_t)4096 * 1024;     // [32 bh][64 d][2048 s]
    bf16* attnb  = vtb + (size_t)4096 * 1024;      // [4096][1024]

    dim3 blk(256);

    // fused casts
    prep<<<dim3(5120), blk, 0, stream>>>(x, w_qkv, w_o, xb, wqkvT, woT);

    // QKV projection (q scaled, k/v row-major; coalesced epilogue)
    gemm_qkv<<<dim3(24, 32), blk, 0, stream>>>(xb, wqkvT, b_qkv, qbuf, kbuf, vbuf);

    // V transpose for attention A-operand staging
    vtrans<<<dim3(32, 32), blk, 0, stream>>>(vbuf, vtb);

    // flash attention: paired causal blocks, K/V double-buffer
    attn_mfma<<<dim3(16, 32), blk, 0, stream>>>(qbuf, kbuf, vtb, attnb);

    // output projection (fp32 out + bias), 512 blocks
    gemm_out<<<dim3(16, 32), blk, 0, stream>>>(attnb, woT, b_o, out);
}

// Round 8
// 179.084 us; speedup vs baseline: 29.9370x; 1.0310x over previous
//
#include <hip/hip_runtime.h>
#include <hip/hip_bf16.h>

typedef __hip_bfloat16 bf16;
typedef unsigned short u16;
typedef __attribute__((ext_vector_type(8))) short short8;
typedef __attribute__((ext_vector_type(4))) float floatx4;

#define D_EMBED 1024
#define N_HEADS 16
#define HEAD_DIM 64
#define BATCH 2
#define SEQ 2048
#define ROWS (BATCH * SEQ)          // 4096
#define QKV_COLS (3 * D_EMBED)      // 3072
// exp2-domain scale folded into Q: log2(e)/sqrt(64)
#define QSCALE 0.1803368801f

__device__ __forceinline__ void g2l16(const void* g, void* l) {
    __builtin_amdgcn_global_load_lds(
        (const __attribute__((address_space(1))) unsigned int*)g,
        (__attribute__((address_space(3))) unsigned int*)l,
        16, 0, 0);
}

__device__ __forceinline__ u16 f2b_bits(float f) {
    bf16 h = __float2bfloat16(f);
    u16 u;
    __builtin_memcpy(&u, &h, 2);
    return u;
}

__device__ __forceinline__ unsigned pack2(float a, float b) {   // RNE pack
    return (unsigned)f2b_bits(a) | ((unsigned)f2b_bits(b) << 16);
}

__device__ __forceinline__ float fexp2(float x) {
#if __has_builtin(__builtin_amdgcn_exp2f)
    return __builtin_amdgcn_exp2f(x);
#else
    return exp2f(x);
#endif
}

// pack two fp32 -> two truncated bf16 in one op (low = a, high = b)
__device__ __forceinline__ unsigned permpack(float a, float b) {
#if __has_builtin(__builtin_amdgcn_perm)
    return __builtin_amdgcn_perm(__float_as_uint(b), __float_as_uint(a), 0x07060302u);
#else
    return (__float_as_uint(a) >> 16) | (__float_as_uint(b) & 0xFFFF0000u);
#endif
}

// ---------------------------------------------------------------------------
// Fused prep: cast x -> bf16; transpose+cast w_qkv, w_o.
// ---------------------------------------------------------------------------
__global__ __launch_bounds__(256)
void prep(const float* __restrict__ x, const float* __restrict__ w_qkv,
          const float* __restrict__ w_o, bf16* __restrict__ xb,
          bf16* __restrict__ wqkvT, bf16* __restrict__ woT)
{
    __shared__ u16 T[64][72];
    const int tid = threadIdx.x;
    const int bid = blockIdx.x;

    if (bid < 4096) {
        const int i = bid * 256 + tid;
        const float4 v = reinterpret_cast<const float4*>(x)[i];
        ushort4 o;
        o.x = f2b_bits(v.x); o.y = f2b_bits(v.y);
        o.z = f2b_bits(v.z); o.w = f2b_bits(v.w);
        reinterpret_cast<ushort4*>(xb)[i] = o;
        return;
    }
    const float* in; u16* out; int R, C, bx, by;
    if (bid < 4864) {
        const int t = bid - 4096;
        in = w_qkv; out = reinterpret_cast<u16*>(wqkvT); R = 1024; C = 3072;
        bx = t % 48; by = t / 48;
    } else {
        const int t = bid - 4864;
        in = w_o; out = reinterpret_cast<u16*>(woT); R = 1024; C = 1024;
        bx = t % 16; by = t / 16;
    }
    const int r0 = by * 64, c0 = bx * 64;
#pragma unroll
    for (int it = 0; it < 4; ++it) {
        const int r = (tid >> 4) + it * 16;
        const int c4 = (tid & 15) * 4;
        const float4 v = *reinterpret_cast<const float4*>(in + (size_t)(r0 + r) * C + c0 + c4);
        T[c4 + 0][r] = f2b_bits(v.x);
        T[c4 + 1][r] = f2b_bits(v.y);
        T[c4 + 2][r] = f2b_bits(v.z);
        T[c4 + 3][r] = f2b_bits(v.w);
    }
    __syncthreads();
#pragma unroll
    for (int it = 0; it < 4; ++it) {
        const int rr = (tid >> 4) + it * 16;
        const int cc4 = (tid & 15) * 4;
        ushort4 o = *reinterpret_cast<const ushort4*>(&T[rr][cc4]);
        *reinterpret_cast<ushort4*>(out + (size_t)(c0 + rr) * R + r0 + cc4) = o;
    }
}

// ---------------------------------------------------------------------------
// QKV MFMA GEMM: C[4096,3072] = A @ Bt^T + bias. 128x128 tile, BK=32.
// Epilogue: q (scaled) / k row-major bf16; V stored TRANSPOSED directly into
// vtb[bh*64+d][s] via per-wave LDS column reads (kills the vtrans kernel).
// ---------------------------------------------------------------------------
__global__ __launch_bounds__(256)
void gemm_qkv(const bf16* __restrict__ A, const bf16* __restrict__ Bt,
              const float* __restrict__ bias,
              bf16* __restrict__ qb, bf16* __restrict__ kb, bf16* __restrict__ vtb)
{
    __shared__ __align__(16) char smem[16384];
    char* As = smem;            // [128 m][32 k] bf16, 64B rows
    char* Bs = smem + 8192;     // [128 n][32 k]

    const int tid = threadIdx.x;
    const int lane = tid & 63, w = tid >> 6;
    const int quad = lane >> 4, l15 = lane & 15;
    const int mw = (w >> 1) * 64, nw = (w & 1) * 64;
    const int blockM = blockIdx.y * 128, blockN = blockIdx.x * 128;

    floatx4 acc[4][4];
#pragma unroll
    for (int i = 0; i < 4; ++i)
#pragma unroll
        for (int j = 0; j < 4; ++j) acc[i][j] = (floatx4){0.f, 0.f, 0.f, 0.f};

    for (int k0 = 0; k0 < 1024; k0 += 32) {
        __syncthreads();
#pragma unroll
        for (int it = 0; it < 2; ++it) {
            const int p = it * 256 + tid;
            const int row = p >> 2, ch = p & 3;
            char* dst = As + (it * 256 + (tid & ~63)) * 16;
            g2l16(A + (size_t)(blockM + row) * 1024 + k0 + ch * 8, dst);
            g2l16(Bt + (size_t)(blockN + row) * 1024 + k0 + ch * 8, dst + 8192);
        }
        __syncthreads();

        short8 af[4], bfr[4];
#pragma unroll
        for (int mi = 0; mi < 4; ++mi)
            af[mi] = *reinterpret_cast<const short8*>(
                As + (mw + mi * 16 + l15) * 64 + quad * 16);
#pragma unroll
        for (int ni = 0; ni < 4; ++ni)
            bfr[ni] = *reinterpret_cast<const short8*>(
                Bs + (nw + ni * 16 + l15) * 64 + quad * 16);
#pragma unroll
        for (int mi = 0; mi < 4; ++mi)
#pragma unroll
            for (int ni = 0; ni < 4; ++ni)
                acc[mi][ni] = __builtin_amdgcn_mfma_f32_16x16x32_bf16(
                    af[mi], bfr[ni], acc[mi][ni], 0, 0, 0);
    }

    // epilogue: per-wave LDS repack
    __syncthreads();
    u16* W = reinterpret_cast<u16*>(smem + w * 2304);   // [16 m][stride 72 u16]
    const bool isq = (blockN < 1024);
    const bool isv = (blockN >= 2048);

    float bvn[4];                        // hoisted bias
#pragma unroll
    for (int ni = 0; ni < 4; ++ni) bvn[ni] = bias[blockN + nw + ni * 16 + l15];

    if (!isv) {
        bf16* dstbuf = isq ? qb : kb;
        const int coloff = blockN - (isq ? 0 : 1024);
#pragma unroll
        for (int mi = 0; mi < 4; ++mi) {
#pragma unroll
            for (int ni = 0; ni < 4; ++ni) {
#pragma unroll
                for (int r = 0; r < 4; ++r) {
                    float val = acc[mi][ni][r] + bvn[ni];
                    if (isq) val *= QSCALE;
                    W[(quad * 4 + r) * 72 + ni * 16 + l15] = f2b_bits(val);
                }
            }
#pragma unroll
            for (int half = 0; half < 2; ++half) {
                const int idx = half * 64 + lane;
                const int rowL = idx >> 3, ch = idx & 7;
                short8 v = *reinterpret_cast<const short8*>(W + rowL * 72 + ch * 8);
                const int grow = blockM + mw + mi * 16 + rowL;
                const int gcol = coloff + nw + ch * 8;
                *reinterpret_cast<short8*>(
                    reinterpret_cast<u16*>(dstbuf) + (size_t)grow * 1024 + gcol) = v;
            }
        }
    } else {
        // V: store transposed to vtb[(b*16+h)*64 + d][s]
        const int col0 = blockN - 2048 + nw;          // multiple of 64
        const int h = col0 >> 6;
        const int bh = (blockM >> 11) * 16 + h;
        const int sb = (blockM & 2047) + mw;
        u16* vdst = reinterpret_cast<u16*>(vtb) + (size_t)bh * 64 * SEQ;
#pragma unroll
        for (int mi = 0; mi < 4; ++mi) {
#pragma unroll
            for (int ni = 0; ni < 4; ++ni) {
#pragma unroll
                for (int r = 0; r < 4; ++r)
                    W[(quad * 4 + r) * 72 + ni * 16 + l15] =
                        f2b_bits(acc[mi][ni][r] + bvn[ni]);
            }
#pragma unroll
            for (int mc = 0; mc < 2; ++mc) {
                u16 tmp[8];
#pragma unroll
                for (int e = 0; e < 8; ++e) tmp[e] = W[(mc * 8 + e) * 72 + lane];
                const int s = sb + mi * 16 + mc * 8;
                *reinterpret_cast<short8*>(vdst + (size_t)lane * SEQ + s) =
                    *reinterpret_cast<const short8*>(tmp);
            }
        }
    }
}

// ---------------------------------------------------------------------------
// Out-proj MFMA GEMM: out[4096,1024] = A @ Bt^T + bias (fp32 out).
// 128m x 64n tile -> 512 blocks (2/CU).
// ---------------------------------------------------------------------------
__global__ __launch_bounds__(256)
void gemm_out(const bf16* __restrict__ A, const bf16* __restrict__ Bt,
              const float* __restrict__ bias, float* __restrict__ outf)
{
    __shared__ __align__(16) char smem[12288];
    char* As = smem;            // [128 m][32 k]
    char* Bs = smem + 8192;     // [64 n][32 k]

    const int tid = threadIdx.x;
    const int lane = tid & 63, w = tid >> 6;
    const int quad = lane >> 4, l15 = lane & 15;
    const int mw = (w >> 1) * 64, nw = (w & 1) * 32;
    const int blockM = blockIdx.y * 128, blockN = blockIdx.x * 64;

    floatx4 acc[4][2];
#pragma unroll
    for (int i = 0; i < 4; ++i)
#pragma unroll
        for (int j = 0; j < 2; ++j) acc[i][j] = (floatx4){0.f, 0.f, 0.f, 0.f};

    for (int k0 = 0; k0 < 1024; k0 += 32) {
        __syncthreads();
#pragma unroll
        for (int it = 0; it < 2; ++it) {
            const int p = it * 256 + tid;
            const int row = p >> 2, ch = p & 3;
            g2l16(A + (size_t)(blockM + row) * 1024 + k0 + ch * 8,
                  As + (it * 256 + (tid & ~63)) * 16);
        }
        {
            const int row = tid >> 2, ch = tid & 3;
            g2l16(Bt + (size_t)(blockN + row) * 1024 + k0 + ch * 8,
                  Bs + (tid & ~63) * 16);
        }
        __syncthreads();

        short8 af[4], bfr[2];
#pragma unroll
        for (int mi = 0; mi < 4; ++mi)
            af[mi] = *reinterpret_cast<const short8*>(
                As + (mw + mi * 16 + l15) * 64 + quad * 16);
#pragma unroll
        for (int ni = 0; ni < 2; ++ni)
            bfr[ni] = *reinterpret_cast<const short8*>(
                Bs + (nw + ni * 16 + l15) * 64 + quad * 16);
#pragma unroll
        for (int mi = 0; mi < 4; ++mi)
#pragma unroll
            for (int ni = 0; ni < 2; ++ni)
                acc[mi][ni] = __builtin_amdgcn_mfma_f32_16x16x32_bf16(
                    af[mi], bfr[ni], acc[mi][ni], 0, 0, 0);
    }

    float bvn[2];
#pragma unroll
    for (int ni = 0; ni < 2; ++ni) bvn[ni] = bias[blockN + nw + ni * 16 + l15];

#pragma unroll
    for (int mi = 0; mi < 4; ++mi)
#pragma unroll
        for (int r = 0; r < 4; ++r) {
            const int row = blockM + mw + mi * 16 + quad * 4 + r;
#pragma unroll
            for (int ni = 0; ni < 2; ++ni) {
                const int col = blockN + nw + ni * 16 + l15;
                outf[(size_t)row * 1024 + col] = acc[mi][ni][r] + bvn[ni];
            }
        }
}

// ---------------------------------------------------------------------------
// MFMA flash attention (causal), max-free exp2-domain softmax.
// MERGED union k-loop: block (i, bh) owns q-tiles qtS=i and qtB=31-i.
// Stage k-tiles 0..31-i ONCE; compute qtB every iteration, qtS while kt<=i.
// Compute perfectly balanced (33 tile-computes/block); K/V fetch down 26%.
// K/V fragments register-shared between the two q-computes.
// Double-buffered K/V; one barrier per k-tile.
// LDS: Q 2x8K | KV dbuf 2x16K | Ps per-wave 4x2K = 56 KB (2 blocks/CU).
// ---------------------------------------------------------------------------
__global__ __launch_bounds__(256)
void attn_mfma(const bf16* __restrict__ qb, const bf16* __restrict__ kb,
               const bf16* __restrict__ vtb, bf16* __restrict__ ob)
{
    __shared__ __align__(16) char smem[57344];
    char* Qs0 = smem;                     // q-tile S, [64 q][64 d] swizzled
    char* Qs1 = smem + 8192;              // q-tile B
    char* KV0 = smem + 16384;             // K 8K + V 8K
    char* KV1 = smem + 32768;
    const int tid = threadIdx.x;
    const int lane = tid & 63, w = tid >> 6;
    const int quad = lane >> 4, l15 = lane & 15;
    char* Ps = smem + 49152 + w * 2048;   // per-wave [8 kchunk][16 q][16B]

    const int pi = blockIdx.x;            // 0..15
    const int bh = blockIdx.y;
    const int b = bh >> 4, h = bh & 15;

    const int qtS = pi, qtB = 31 - pi;
    const int q0S = qtS * 64, q0B = qtB * 64;
    const int KT = qtB + 1;
    const int qrowS = q0S + w * 16 + l15;
    const int qrowB = q0B + w * 16 + l15;

    const size_t kvrow = (size_t)b * SEQ;
    const size_t vbase = (size_t)bh * 64 * SEQ;

    const short8 ones = {0x3F80, 0x3F80, 0x3F80, 0x3F80,
                         0x3F80, 0x3F80, 0x3F80, 0x3F80};   // bf16 1.0 x8

    // stage both Q tiles + K/V tile kt=0
#pragma unroll
    for (int it = 0; it < 2; ++it) {
        const int p = it * 256 + tid;
        const int row = p >> 3;
        const int lch = (p & 7) ^ (row & 7);
        const int loff = (it * 256 + (tid & ~63)) * 16;
        g2l16(qb + (kvrow + q0S + row) * D_EMBED + h * 64 + lch * 8, Qs0 + loff);
        g2l16(qb + (kvrow + q0B + row) * D_EMBED + h * 64 + lch * 8, Qs1 + loff);
        g2l16(kb + (kvrow + row) * D_EMBED + h * 64 + lch * 8, KV0 + loff);
        g2l16(vtb + vbase + (size_t)row * SEQ + lch * 8, KV0 + 8192 + loff);
    }
    __syncthreads();

    const int qoff = (w * 16 + l15) * 128;
    const int x0 = (quad ^ (l15 & 7)) * 16;
    const int x1 = ((quad + 4) ^ (l15 & 7)) * 16;
    const short8 qS0 = *reinterpret_cast<const short8*>(Qs0 + qoff + x0);
    const short8 qS1 = *reinterpret_cast<const short8*>(Qs0 + qoff + x1);
    const short8 qB0 = *reinterpret_cast<const short8*>(Qs1 + qoff + x0);
    const short8 qB1 = *reinterpret_cast<const short8*>(Qs1 + qoff + x1);

    floatx4 OaccS[4], OaccB[4], LaccS, LaccB;
#pragma unroll
    for (int i = 0; i < 4; ++i) {
        OaccS[i] = (floatx4){0.f, 0.f, 0.f, 0.f};
        OaccB[i] = (floatx4){0.f, 0.f, 0.f, 0.f};
    }
    LaccS = (floatx4){0.f, 0.f, 0.f, 0.f};
    LaccB = (floatx4){0.f, 0.f, 0.f, 0.f};

#pragma unroll 1
    for (int kt = 0; kt < KT; ++kt) {
        char* cur = (kt & 1) ? KV1 : KV0;
        if (kt + 1 < KT) {                      // prefetch next K/V tile
            char* nxt = (kt & 1) ? KV0 : KV1;
            const int nk0 = (kt + 1) * 64;
#pragma unroll
            for (int it = 0; it < 2; ++it) {
                const int p = it * 256 + tid;
                const int row = p >> 3;
                const int lch = (p & 7) ^ (row & 7);
                char* dst = nxt + (it * 256 + (tid & ~63)) * 16;
                g2l16(kb + (kvrow + nk0 + row) * D_EMBED + h * 64 + lch * 8, dst);
                g2l16(vtb + vbase + (size_t)row * SEQ + nk0 + lch * 8, dst + 8192);
            }
        }
        const int k0 = kt * 64;
        char* Ks = cur;
        char* Vs = cur + 8192;

        // load K/V fragments once, share across both q-computes
        short8 kf[2][4], vf[2][4];
#pragma unroll
        for (int ms = 0; ms < 4; ++ms) {
            const int roff = (ms * 16 + l15) * 128;
            kf[0][ms] = *reinterpret_cast<const short8*>(Ks + roff + x0);
            kf[1][ms] = *reinterpret_cast<const short8*>(Ks + roff + x1);
        }
#pragma unroll
        for (int ks = 0; ks < 2; ++ks)
#pragma unroll
            for (int ds = 0; ds < 4; ++ds)
                vf[ks][ds] = *reinterpret_cast<const short8*>(
                    Vs + (ds * 16 + l15) * 128 + (((quad + ks * 4) ^ (l15 & 7)) * 16));

        // ---- big q-tile (always) ----
        {
            floatx4 S[4];
#pragma unroll
            for (int ms = 0; ms < 4; ++ms) {
                floatx4 t = (floatx4){0.f, 0.f, 0.f, 0.f};
                t = __builtin_amdgcn_mfma_f32_16x16x32_bf16(kf[0][ms], qB0, t, 0, 0, 0);
                S[ms] = __builtin_amdgcn_mfma_f32_16x16x32_bf16(kf[1][ms], qB1, t, 0, 0, 0);
            }
            const bool diag = (kt == KT - 1);
#pragma unroll
            for (int ms = 0; ms < 4; ++ms) {
                float p[4];
#pragma unroll
                for (int r = 0; r < 4; ++r) {
                    float s = S[ms][r];
                    if (diag && (k0 + ms * 16 + quad * 4 + r) > qrowB) s = -1e30f;
                    p[r] = fexp2(s);
                }
                const int k = ms * 16 + quad * 4;
                uint2 pw;
                pw.x = permpack(p[0], p[1]);
                pw.y = permpack(p[2], p[3]);
                *reinterpret_cast<uint2*>(Ps + (k >> 3) * 256 + l15 * 16 + (k & 7) * 2) = pw;
            }
#pragma unroll
            for (int ks = 0; ks < 2; ++ks) {
                const short8 pf = *reinterpret_cast<const short8*>(
                    Ps + (ks * 4 + quad) * 256 + l15 * 16);
                LaccB = __builtin_amdgcn_mfma_f32_16x16x32_bf16(ones, pf, LaccB, 0, 0, 0);
#pragma unroll
                for (int ds = 0; ds < 4; ++ds)
                    OaccB[ds] = __builtin_amdgcn_mfma_f32_16x16x32_bf16(
                        vf[ks][ds], pf, OaccB[ds], 0, 0, 0);
            }
        }

        // ---- small q-tile (while kt <= qtS) ----
        if (kt <= qtS) {
            floatx4 S[4];
#pragma unroll
            for (int ms = 0; ms < 4; ++ms) {
                floatx4 t = (floatx4){0.f, 0.f, 0.f, 0.f};
                t = __builtin_amdgcn_mfma_f32_16x16x32_bf16(kf[0][ms], qS0, t, 0, 0, 0);
                S[ms] = __builtin_amdgcn_mfma_f32_16x16x32_bf16(kf[1][ms], qS1, t, 0, 0, 0);
            }
            const bool diag = (kt == qtS);
#pragma unroll
            for (int ms = 0; ms < 4; ++ms) {
                float p[4];
#pragma unroll
                for (int r = 0; r < 4; ++r) {
                    float s = S[ms][r];
                    if (diag && (k0 + ms * 16 + quad * 4 + r) > qrowS) s = -1e30f;
                    p[r] = fexp2(s);
                }
                const int k = ms * 16 + quad * 4;
                uint2 pw;
                pw.x = permpack(p[0], p[1]);
                pw.y = permpack(p[2], p[3]);
                *reinterpret_cast<uint2*>(Ps + (k >> 3) * 256 + l15 * 16 + (k & 7) * 2) = pw;
            }
#pragma unroll
            for (int ks = 0; ks < 2; ++ks) {
                const short8 pf = *reinterpret_cast<const short8*>(
                    Ps + (ks * 4 + quad) * 256 + l15 * 16);
                LaccS = __builtin_amdgcn_mfma_f32_16x16x32_bf16(ones, pf, LaccS, 0, 0, 0);
#pragma unroll
                for (int ds = 0; ds < 4; ++ds)
                    OaccS[ds] = __builtin_amdgcn_mfma_f32_16x16x32_bf16(
                        vf[ks][ds], pf, OaccS[ds], 0, 0, 0);
            }
        }
        __syncthreads();   // publish prefetched tile; frees cur for restage
    }

    // epilogue: O^T/l -> per-wave LDS [q][d] -> coalesced 16B stores (both tiles)
#pragma unroll
    for (int which = 0; which < 2; ++which) {
        const floatx4* Oacc = which ? OaccB : OaccS;
        const float invl = 1.f / (which ? LaccB[0] : LaccS[0]);
        const int q0 = which ? q0B : q0S;
#pragma unroll
        for (int ds = 0; ds < 4; ++ds) {
            const int d = ds * 16 + quad * 4;
            uint2 ow;
            ow.x = pack2(Oacc[ds][0] * invl, Oacc[ds][1] * invl);
            ow.y = pack2(Oacc[ds][2] * invl, Oacc[ds][3] * invl);
            *reinterpret_cast<uint2*>(
                Ps + (d >> 3) * 256 + l15 * 16 + (d & 7) * 2) = ow;
        }
#pragma unroll
        for (int it = 0; it < 2; ++it) {
            const int idx = it * 64 + lane;
            const int ch = idx >> 4, q = idx & 15;
            short8 ov = *reinterpret_cast<const short8*>(Ps + ch * 256 + q * 16);
            *reinterpret_cast<short8*>(
                ob + (kvrow + q0 + w * 16 + q) * D_EMBED + h * 64 + ch * 8) = ov;
        }
    }
}

// ---------------------------------------------------------------------------
extern "C" void kernel_launch(void* const* d_in, const int* in_sizes, int n_in,
                              void* d_out, int out_size, void* d_ws, size_t ws_size,
                              hipStream_t stream)
{
    const float* x     = (const float*)d_in[0];   // [4096, 1024]
    const float* w_qkv = (const float*)d_in[1];   // [1024, 3072]
    const float* b_qkv = (const float*)d_in[2];   // [3072]
    const float* w_o   = (const float*)d_in[3];   // [1024, 1024]
    const float* b_o   = (const float*)d_in[4];   // [1024]
    float* out = (float*)d_out;                   // [4096, 1024] fp32

    bf16* xb     = (bf16*)d_ws;                    // [4096][1024]
    bf16* wqkvT  = xb + (size_t)4096 * 1024;       // [3072][1024]
    bf16* woT    = wqkvT + (size_t)3072 * 1024;    // [1024][1024]
    bf16* qbuf   = woT + (size_t)1024 * 1024;      // [4096][1024] (pre-scaled)
    bf16* kbuf   = qbuf + (size_t)4096 * 1024;     // [4096][1024]
    bf16* vtb    = kbuf + (size_t)4096 * 1024;     // [32 bh][64 d][2048 s]
    bf16* attnb  = vtb + (size_t)4096 * 1024;      // [4096][1024]

    dim3 blk(256);

    // fused casts
    prep<<<dim3(5120), blk, 0, stream>>>(x, w_qkv, w_o, xb, wqkvT, woT);

    // QKV projection (q scaled, k row-major, V transposed directly)
    gemm_qkv<<<dim3(24, 32), blk, 0, stream>>>(xb, wqkvT, b_qkv, qbuf, kbuf, vtb);

    // flash attention: merged-pair causal blocks, K/V double-buffer
    attn_mfma<<<dim3(16, 32), blk, 0, stream>>>(qbuf, kbuf, vtb, attnb);

    // output projection (fp32 out + bias), 512 blocks
    gemm_out<<<dim3(16, 32), blk, 0, stream>>>(attnb, woT, b_o, out);
}